// Round 24
// baseline (491.041 us; speedup 1.0000x reference)
//
#include <hip/hip_runtime.h>
#include <cstdint>

// HEADS=16, DIM=1024, SEQ=512, MEM=512, CMEM=128, RATIO=4, DIM_H=64, b=8, kv_len=1152

typedef __bf16 bf16;
typedef __bf16 bf16x2 __attribute__((ext_vector_type(2)));
typedef __bf16 bf16x4 __attribute__((ext_vector_type(4)));
typedef __bf16 bf16x8 __attribute__((ext_vector_type(8)));
typedef float  f32x2  __attribute__((ext_vector_type(2)));
typedef float  f32x4  __attribute__((ext_vector_type(4)));

#define GLOAD_LDS16(g, l) \
    __builtin_amdgcn_global_load_lds((const __attribute__((address_space(1))) void*)(g), \
                                     (__attribute__((address_space(3))) void*)(l), 16, 0, 0)

// ---------------------------------------------------------------------------
// GEMM body: tile 128x128, BK=32, 4 waves, global_load_lds staging, XOR swizzle.
// ---------------------------------------------------------------------------
template<int AMODE, int EPI>
__device__ __forceinline__ void gemm_body(
    int bx, int by, int bz,
    const bf16* __restrict__ A, const bf16* __restrict__ B2,
    float* __restrict__ C, bf16* __restrict__ outB, bf16* __restrict__ vT,
    int N, int K, int lda, int ldbt, int ldc,
    const float* __restrict__ bias, int vrows,
    const bf16* __restrict__ gcmem, const bf16* __restrict__ gmem,
    const bf16* __restrict__ gx,
    bf16* As, bf16* Bs)
{
    int row0 = by * 128, col0 = bx * 128;
    int tid = threadIdx.x;
    int kofs = (EPI == 8) ? bz * K : 0;

    int lane = tid & 63, wid = tid >> 6;
    int wr = wid >> 1, wc = wid & 1;
    int fr = lane & 15, fq = lane >> 4;

    int srow = lane >> 2;
    int sc16 = (lane & 3) ^ ((lane >> 3) & 3);
    const bf16* aq[2];
    const bf16* bq[2];
    bf16* as_dst[2];
    bf16* bs_dst[2];
#pragma unroll
    for (int t = 0; t < 2; t++) {
        int gr = row0 + wid * 32 + t * 16 + srow;
        const bf16* ap;
        if (AMODE == 0) {
            ap = A + (long)gr * lda + kofs;
        } else {
            int bb = gr / 1152, rr = gr - bb * 1152;
            ap = (rr < 128) ? (gcmem + ((long)bb * 128 + rr) * 1024)
               : (rr < 640) ? (gmem + ((long)bb * 512 + (rr - 128)) * 1024)
                            : (gx   + ((long)bb * 512 + (rr - 640)) * 1024);
        }
        aq[t] = ap + sc16 * 8;
        int gc = col0 + wid * 32 + t * 16 + srow;
        bq[t] = B2 + (long)gc * ldbt + kofs + sc16 * 8;
        as_dst[t] = &As[(wid * 32 + t * 16) * 32];
        bs_dst[t] = &Bs[(wid * 32 + t * 16) * 32];
    }

    int sfq = (fq ^ ((fr >> 1) & 3)) * 8;

    f32x4 acc[4][4];
#pragma unroll
    for (int i = 0; i < 4; i++)
#pragma unroll
        for (int j = 0; j < 4; j++) acc[i][j] = (f32x4){0.f, 0.f, 0.f, 0.f};

    for (int k0 = 0; k0 < K; k0 += 32) {
#pragma unroll
        for (int t = 0; t < 2; t++) {
            GLOAD_LDS16(aq[t] + k0, as_dst[t]);
            GLOAD_LDS16(bq[t] + k0, bs_dst[t]);
        }
        __syncthreads();

        bf16x8 af[4], bfv[4];
#pragma unroll
        for (int i = 0; i < 4; i++)
            af[i] = *(const bf16x8*)&As[(wr * 64 + i * 16 + fr) * 32 + sfq];
#pragma unroll
        for (int j = 0; j < 4; j++)
            bfv[j] = *(const bf16x8*)&Bs[(wc * 64 + j * 16 + fr) * 32 + sfq];
#pragma unroll
        for (int i = 0; i < 4; i++)
#pragma unroll
            for (int j = 0; j < 4; j++)
                acc[i][j] = __builtin_amdgcn_mfma_f32_16x16x32_bf16(af[i], bfv[j], acc[i][j], 0, 0, 0);
        __syncthreads();
    }

#pragma unroll
    for (int i = 0; i < 4; i++) {
#pragma unroll
        for (int j = 0; j < 4; j++) {
#pragma unroll
            for (int g = 0; g < 4; g++) {
                int r = row0 + wr * 64 + i * 16 + fq * 4 + g;
                int c = col0 + wc * 64 + j * 16 + fr;
                float v = acc[i][j][g];
                if (EPI == 0) {
                    if (bias) v += bias[c];
                    C[(long)r * ldc + c] = v;
                } else if (EPI == 6) {
                    if (bias) v += bias[c];
                    __builtin_nontemporal_store(v, &C[(long)r * ldc + c]);
                } else if (EPI == 8) {
                    C[((long)bz << 20) + (long)r * 1024 + c] = v;
                } else if (EPI == 4) {
                    outB[(long)r * ldc + c] = (bf16)v;
                } else { // EPI == 5
                    if (c < 1024) {
                        outB[(long)r * 1024 + c] = (bf16)v;
                    } else {
                        int d = c - 1024; int hh = d >> 6; d &= 63;
                        int bb = r / vrows; int j2 = r - bb * vrows;
                        vT[(((long)(bb * 16 + hh)) * 64 + d) * vrows + j2] = (bf16)v;
                    }
                }
            }
        }
    }
}

// ---------------------------------------------------------------------------
// aux body (round-10 structure), shared carved from pool.
// ---------------------------------------------------------------------------
__device__ __forceinline__ void aux_body(
    int bx, int by,
    const bf16* __restrict__ qb, const bf16* __restrict__ kb,
    const bf16* __restrict__ ckb,
    const bf16* __restrict__ vTb, const bf16* __restrict__ cvT,
    float* __restrict__ partials,
    bf16* qs, bf16* upool, bf16* vt, float* wred)
{
    int z = by;
    int b = z >> 4, h = z & 15;
    int r0 = bx * 128;
    int tid = threadIdx.x;
    int lane = tid & 63, wid = tid >> 6;
    int fr = lane & 15, fq = lane >> 4;

#pragma unroll
    for (int t = 0; t < 4; t++) {
        int e = tid + 256 * t; int rr = e >> 3, c8 = (e & 7) * 8;
        *(bf16x8*)&qs[rr * 72 + c8] = *(const bf16x8*)&qb[((long)(b * 512 + r0 + rr)) * 1024 + h * 64 + c8];
    }

    float o1[2][4][4];
    f32x4 oaccv[2][4];
    float mrow[2][4], lrow[2][4];
    f32x4 sacc[2][8];
    float local = 0.f;

    for (int pass = 0; pass < 2; pass++) {
#pragma unroll
        for (int i = 0; i < 2; i++)
#pragma unroll
            for (int g = 0; g < 4; g++) { mrow[i][g] = -3.4e38f; lrow[i][g] = 0.f; }
#pragma unroll
        for (int i = 0; i < 2; i++)
#pragma unroll
            for (int jd = 0; jd < 4; jd++) oaccv[i][jd] = (f32x4){0.f, 0.f, 0.f, 0.f};

        int nchunk = pass ? 1 : 4;
        for (int jt = 0; jt < nchunk; jt++) {
            __syncthreads();
            if (pass == 0) {
                long base = (long)(b * 1152 + 128 + jt * 128);
#pragma unroll
                for (int t = 0; t < 4; t++) {
                    int e = tid + 256 * t; int j = e >> 3, c8 = (e & 7) * 8;
                    *(bf16x8*)&upool[j * 72 + c8] = *(const bf16x8*)&kb[(base + j) * 1024 + h * 64 + c8];
                }
#pragma unroll
                for (int t = 0; t < 4; t++) {
                    int e = tid + 256 * t; int d = e >> 4, j8 = (e & 15) * 8;
                    *(bf16x8*)&vt[d * 136 + j8] =
                        *(const bf16x8*)&vTb[((long)z * 64 + d) * 1152 + 128 + jt * 128 + j8];
                }
            } else {
#pragma unroll
                for (int t = 0; t < 4; t++) {
                    int e = tid + 256 * t; int j = e >> 3, c8 = (e & 7) * 8;
                    *(bf16x8*)&upool[j * 72 + c8] = *(const bf16x8*)&ckb[((long)(b * 128 + j)) * 1024 + h * 64 + c8];
                }
#pragma unroll
                for (int t = 0; t < 4; t++) {
                    int e = tid + 256 * t; int d = e >> 4, j8 = (e & 15) * 8;
                    *(bf16x8*)&vt[d * 136 + j8] = *(const bf16x8*)&cvT[((long)z * 64 + d) * 128 + j8];
                }
            }
            __syncthreads();

#pragma unroll
            for (int i = 0; i < 2; i++)
#pragma unroll
                for (int j = 0; j < 8; j++) sacc[i][j] = (f32x4){0.f, 0.f, 0.f, 0.f};
#pragma unroll
            for (int s = 0; s < 2; s++) {
                bf16x8 af[2], bfv[8];
#pragma unroll
                for (int i = 0; i < 2; i++)
                    af[i] = *(const bf16x8*)&qs[(wid * 32 + i * 16 + fr) * 72 + s * 32 + fq * 8];
#pragma unroll
                for (int j = 0; j < 8; j++)
                    bfv[j] = *(const bf16x8*)&upool[(j * 16 + fr) * 72 + s * 32 + fq * 8];
#pragma unroll
                for (int i = 0; i < 2; i++)
#pragma unroll
                    for (int j = 0; j < 8; j++)
                        sacc[i][j] = __builtin_amdgcn_mfma_f32_16x16x32_bf16(af[i], bfv[j], sacc[i][j], 0, 0, 0);
            }
            __syncthreads();

#pragma unroll
            for (int i = 0; i < 2; i++) {
#pragma unroll
                for (int g = 0; g < 4; g++) {
                    float mx = -3.4e38f;
#pragma unroll
                    for (int j = 0; j < 8; j++) mx = fmaxf(mx, sacc[i][j][g]);
                    mx *= 0.125f;
#pragma unroll
                    for (int msk = 1; msk <= 8; msk <<= 1) mx = fmaxf(mx, __shfl_xor(mx, msk, 64));
                    float mnew = fmaxf(mrow[i][g], mx);
                    float alpha = __expf(mrow[i][g] - mnew);
                    mrow[i][g] = mnew;
                    float sum = 0.f;
                    int prow = (wid * 32 + i * 16 + fq * 4 + g) * 136;
#pragma unroll
                    for (int j = 0; j < 8; j++) {
                        float p = __expf(sacc[i][j][g] * 0.125f - mnew);
                        sum += p;
                        upool[prow + j * 16 + fr] = (bf16)p;
                    }
#pragma unroll
                    for (int msk = 1; msk <= 8; msk <<= 1) sum += __shfl_xor(sum, msk, 16);
                    lrow[i][g] = lrow[i][g] * alpha + sum;
#pragma unroll
                    for (int jd = 0; jd < 4; jd++) oaccv[i][jd][g] *= alpha;
                }
            }
            __syncthreads();

#pragma unroll
            for (int s2 = 0; s2 < 4; s2++) {
                bf16x8 pa[2], vb[4];
#pragma unroll
                for (int i = 0; i < 2; i++)
                    pa[i] = *(const bf16x8*)&upool[(wid * 32 + i * 16 + fr) * 136 + s2 * 32 + fq * 8];
#pragma unroll
                for (int jd = 0; jd < 4; jd++)
                    vb[jd] = *(const bf16x8*)&vt[(jd * 16 + fr) * 136 + s2 * 32 + fq * 8];
#pragma unroll
                for (int i = 0; i < 2; i++)
#pragma unroll
                    for (int jd = 0; jd < 4; jd++)
                        oaccv[i][jd] = __builtin_amdgcn_mfma_f32_16x16x32_bf16(pa[i], vb[jd], oaccv[i][jd], 0, 0, 0);
            }
        }

        if (pass == 0) {
#pragma unroll
            for (int i = 0; i < 2; i++)
#pragma unroll
                for (int jd = 0; jd < 4; jd++)
#pragma unroll
                    for (int g = 0; g < 4; g++)
                        o1[i][jd][g] = oaccv[i][jd][g] / lrow[i][g];
        } else {
#pragma unroll
            for (int i = 0; i < 2; i++)
#pragma unroll
                for (int jd = 0; jd < 4; jd++)
#pragma unroll
                    for (int g = 0; g < 4; g++) {
                        float dd = o1[i][jd][g] - oaccv[i][jd][g] / lrow[i][g];
                        local += dd * dd;
                    }
        }
    }

#pragma unroll
    for (int off = 32; off; off >>= 1) local += __shfl_xor(local, off, 64);
    if (lane == 0) wred[wid] = local;
    __syncthreads();
    if (tid == 0)
        partials[(long)by * 4 + bx] = wred[0] + wred[1] + wred[2] + wred[3];
}

// ---------------------------------------------------------------------------
// Launch A: kv (0..1151) | q (1152..1407) | conv split-K (1408..1663)
// ---------------------------------------------------------------------------
__global__ __launch_bounds__(256)
void gemmA_kernel(const bf16* __restrict__ xb, const bf16* __restrict__ memb,
                  const bf16* __restrict__ cmemb,
                  const bf16* __restrict__ WqTb, const bf16* __restrict__ WkvTb,
                  const bf16* __restrict__ convwTb,
                  bf16* __restrict__ qb, bf16* __restrict__ kb, bf16* __restrict__ vTb,
                  float* __restrict__ pbuf)
{
    __shared__ bf16 As[128 * 32];
    __shared__ bf16 Bs[128 * 32];
    int gid = blockIdx.x;
    if (gid < 1152) {
        gemm_body<1, 5>(gid % 16, gid / 16, 0, nullptr, WkvTb, nullptr, kb, vTb,
                        2048, 1024, 1024, 1024, 2048, nullptr, 1152,
                        cmemb, memb, xb, As, Bs);
    } else if (gid < 1408) {
        int g = gid - 1152;
        gemm_body<0, 4>(g % 8, g / 8, 0, xb, WqTb, nullptr, qb, nullptr,
                        1024, 1024, 1024, 1024, 1024, nullptr, 0,
                        nullptr, nullptr, nullptr, As, Bs);
    } else {
        int g = gid - 1408;
        gemm_body<0, 8>(g % 8, (g / 8) % 8, g / 64, memb, convwTb, pbuf, nullptr, nullptr,
                        1024, 1024, 4096, 4096, 1024, nullptr, 0,
                        nullptr, nullptr, nullptr, As, Bs);
    }
}

// ckv standalone: 128 blocks
__global__ __launch_bounds__(256)
void ckv_kernel(const bf16* __restrict__ ncmemb, const bf16* __restrict__ WkvTb,
                bf16* __restrict__ ckb, bf16* __restrict__ cvT)
{
    __shared__ bf16 As[128 * 32];
    __shared__ bf16 Bs[128 * 32];
    gemm_body<0, 5>(blockIdx.x % 16, blockIdx.x / 16, 0, ncmemb, WkvTb, nullptr, ckb, cvT,
                    2048, 1024, 1024, 1024, 2048, nullptr, 128,
                    nullptr, nullptr, nullptr, As, Bs);
}

// ---------------------------------------------------------------------------
// Fused attention (round-10 structure + full unroll + setprio on PV)
// ---------------------------------------------------------------------------
#define SSTR 1164

__global__ __launch_bounds__(256)
void attn_fused16(const bf16* __restrict__ qb, const bf16* __restrict__ kb,
                  const bf16* __restrict__ peb, const bf16* __restrict__ vTb,
                  float* __restrict__ weights, bf16* __restrict__ oatb)
{
    int bid = blockIdx.x;
    int w = (bid & 7) * 512 + (bid >> 3);
    int z = w >> 5;
    int b = z >> 4, h = z & 15;
    int r0 = (w & 31) * 16;
    int tid = threadIdx.x;
    int lane = tid & 63, wid = tid >> 6;
    int fr = lane & 15, fq = lane >> 4;

    __shared__ bf16 S[16 * SSTR];

    bf16x8 afr[2];
#pragma unroll
    for (int ks = 0; ks < 2; ks++)
        afr[ks] = *(const bf16x8*)&qb[((long)(b * 512 + r0 + fr)) * 1024 + h * 64 + ks * 32 + fq * 8];

#pragma unroll
    for (int ch = 0; ch < 9; ch++) {
        int c0 = ch * 128;
        int jb0 = c0 + 496 - r0 + 32 * wid;

        f32x4 p[3];
#pragma unroll
        for (int ct = 0; ct < 3; ct++) {
            f32x4 a = (f32x4){0.f, 0.f, 0.f, 0.f};
            int j = jb0 + ct * 16 + fr;
            bool ok = (j < 1152);
#pragma unroll
            for (int ks = 0; ks < 2; ks++) {
                bf16x8 bv = {};
                if (ok) bv = *(const bf16x8*)&peb[((long)(h * 1152 + j)) * 64 + ks * 32 + fq * 8];
                a = __builtin_amdgcn_mfma_f32_16x16x32_bf16(afr[ks], bv, a, 0, 0, 0);
            }
            p[ct] = a;
        }

#pragma unroll
        for (int tt = 0; tt < 2; tt++) {
            int cc = 32 * wid + 16 * tt + fr;
            f32x4 a = (f32x4){0.f, 0.f, 0.f, 0.f};
            long krow = (long)(b * 1152 + c0 + cc);
#pragma unroll
            for (int ks = 0; ks < 2; ks++) {
                bf16x8 bv = *(const bf16x8*)&kb[krow * 1024 + h * 64 + ks * 32 + fq * 8];
                a = __builtin_amdgcn_mfma_f32_16x16x32_bf16(afr[ks], bv, a, 0, 0, 0);
            }
#pragma unroll
            for (int g = 0; g < 4; g++) {
                int rr = fq * 4 + g;
                int uu = fr + 15 - rr;
                int src = (uu & 15) | (fq << 4);
                float s0 = __shfl(p[tt][g], src, 64);
                float s1 = __shfl(p[tt + 1][g], src, 64);
                float pv = (uu < 16) ? s0 : s1;
                S[rr * SSTR + c0 + cc] = (bf16)(0.125f * (a[g] + pv));
            }
        }
    }
    __syncthreads();

    for (int rw = 0; rw < 4; rw++) {
        int row = wid * 4 + rw;
        bf16* Srow = &S[row * SSTR];
        bf16x8 v0 = *(const bf16x8*)&Srow[lane * 8];
        bf16x8 v1 = *(const bf16x8*)&Srow[512 + lane * 8];
        bf16x2 v2 = *(const bf16x2*)&Srow[1024 + lane * 2];
        float e[18];
#pragma unroll
        for (int j = 0; j < 8; j++) { e[j] = (float)v0[j]; e[8 + j] = (float)v1[j]; }
        e[16] = (float)v2[0]; e[17] = (float)v2[1];

        float m = e[0];
#pragma unroll
        for (int k = 1; k < 18; k++) m = fmaxf(m, e[k]);
#pragma unroll
        for (int off = 32; off; off >>= 1) m = fmaxf(m, __shfl_xor(m, off, 64));
        float sm = 0.f;
#pragma unroll
        for (int k = 0; k < 18; k++) { e[k] = __expf(e[k] - m); sm += e[k]; }
#pragma unroll
        for (int off = 32; off; off >>= 1) sm += __shfl_xor(sm, off, 64);
        float inv = 1.f / sm;

        bf16x8 w0, w1; bf16x2 w2;
#pragma unroll
        for (int j = 0; j < 8; j++) { w0[j] = (bf16)(e[j] * inv); w1[j] = (bf16)(e[8 + j] * inv); }
        w2[0] = (bf16)(e[16] * inv); w2[1] = (bf16)(e[17] * inv);
        *(bf16x8*)&Srow[lane * 8] = w0;
        *(bf16x8*)&Srow[512 + lane * 8] = w1;
        *(bf16x2*)&Srow[1024 + lane * 2] = w2;
    }
    __syncthreads();

    f32x4 oacc = (f32x4){0.f, 0.f, 0.f, 0.f};
    int dt = wid;
    __builtin_amdgcn_s_setprio(1);
    for (int ch = 0; ch < 9; ch++) {
        int c0 = ch * 128;
#pragma unroll
        for (int ks = 0; ks < 4; ks++) {
            bf16x8 pa = *(const bf16x8*)&S[fr * SSTR + c0 + ks * 32 + fq * 8];
            bf16x8 vb = *(const bf16x8*)&vTb[((long)z * 64 + dt * 16 + fr) * 1152 + c0 + ks * 32 + fq * 8];
            oacc = __builtin_amdgcn_mfma_f32_16x16x32_bf16(pa, vb, oacc, 0, 0, 0);
        }
    }
    __builtin_amdgcn_s_setprio(0);
#pragma unroll
    for (int g = 0; g < 4; g++)
        oatb[((long)(b * 512 + r0 + fq * 4 + g)) * 1024 + h * 64 + dt * 16 + fr] = (bf16)oacc[g];

    for (int rw = 0; rw < 4; rw++) {
        int row = wid * 4 + rw;
        const bf16* Srow = &S[row * SSTR];
        long wbase = ((long)z * 512 + r0 + row) * 1152;
        bf16x8 v0 = *(const bf16x8*)&Srow[lane * 8];
        bf16x8 v1 = *(const bf16x8*)&Srow[512 + lane * 8];
        bf16x2 v2 = *(const bf16x2*)&Srow[1024 + lane * 2];
        f32x4 a0 = { (float)v0[0], (float)v0[1], (float)v0[2], (float)v0[3] };
        f32x4 a1 = { (float)v0[4], (float)v0[5], (float)v0[6], (float)v0[7] };
        f32x4 b0 = { (float)v1[0], (float)v1[1], (float)v1[2], (float)v1[3] };
        f32x4 b1 = { (float)v1[4], (float)v1[5], (float)v1[6], (float)v1[7] };
        f32x2 c0 = { (float)v2[0], (float)v2[1] };
        __builtin_nontemporal_store(a0, (f32x4*)&weights[wbase + lane * 8]);
        __builtin_nontemporal_store(a1, (f32x4*)&weights[wbase + lane * 8 + 4]);
        __builtin_nontemporal_store(b0, (f32x4*)&weights[wbase + 512 + lane * 8]);
        __builtin_nontemporal_store(b1, (f32x4*)&weights[wbase + 512 + lane * 8 + 4]);
        __builtin_nontemporal_store(c0, (f32x2*)&weights[wbase + 1024 + lane * 2]);
    }
}

// Launch C: aux (0..511) | logits (512..767)
__global__ __launch_bounds__(256)
void logits_aux_kernel(const bf16* __restrict__ qb, const bf16* __restrict__ kb,
                       const bf16* __restrict__ ckb,
                       const bf16* __restrict__ vTb, const bf16* __restrict__ cvT,
                       float* __restrict__ partials,
                       const bf16* __restrict__ oatb, const bf16* __restrict__ WoutTb,
                       float* __restrict__ out_logits, const float* __restrict__ bout)
{
    __shared__ bf16 pool[35328];   // qs 9216 | upool 17408 | vt 8704
    __shared__ float wred[4];
    int gid = blockIdx.x;
    if (gid < 512) {
        aux_body(gid % 4, gid / 4, qb, kb, ckb, vTb, cvT, partials,
                 pool, pool + 9216, pool + 26624, wred);
    } else {
        int g = gid - 512;
        gemm_body<0, 6>(g % 8, g / 8, 0, oatb, WoutTb, out_logits, nullptr, nullptr,
                        1024, 1024, 1024, 1024, 1024, bout, 0,
                        nullptr, nullptr, nullptr, pool, pool + 4096);
    }
}

// split-K reduce
__global__ __launch_bounds__(256)
void splitk_reduce(const float* __restrict__ pbuf, const float* __restrict__ bias,
                   float* __restrict__ outF, bf16* __restrict__ outB)
{
    int i = blockIdx.x * 256 + threadIdx.x;
    f32x4 s = reinterpret_cast<const f32x4*>(pbuf)[i];
#pragma unroll
    for (int k = 1; k < 4; k++) {
        f32x4 t = reinterpret_cast<const f32x4*>(pbuf + (long)k * 1048576)[i];
        s[0] += t[0]; s[1] += t[1]; s[2] += t[2]; s[3] += t[3];
    }
    int col4 = (i << 2) & 1023;
    f32x4 bv = *(const f32x4*)&bias[col4];
    s[0] += bv[0]; s[1] += bv[1]; s[2] += bv[2]; s[3] += bv[3];
    reinterpret_cast<f32x4*>(outF)[i] = s;
    bf16x4 h = { (bf16)s[0], (bf16)s[1], (bf16)s[2], (bf16)s[3] };
    reinterpret_cast<bf16x4*>(outB)[i] = h;
}

// ---------------------------------------------------------------------------
// Prologue bodies
// ---------------------------------------------------------------------------
__device__ __forceinline__ void transpose_body(
    int bx, int by, const float* __restrict__ in, bf16* __restrict__ out,
    int R, int C, float* t /* 32*33 floats */)
{
    int c0 = bx * 32, r0 = by * 32;
    int tx = threadIdx.x & 31, ty = threadIdx.x >> 5;
#pragma unroll
    for (int i = 0; i < 32; i += 8)
        t[(ty + i) * 33 + tx] = in[(long)(r0 + ty + i) * C + c0 + tx];
    __syncthreads();
#pragma unroll
    for (int i = 0; i < 32; i += 8)
        out[(long)(c0 + ty + i) * R + r0 + tx] = (bf16)t[tx * 33 + ty + i];
}

__device__ __forceinline__ void convw_body(
    int o, const float* __restrict__ cw, bf16* __restrict__ out, float* t /*4096*/)
{
    const float* src = cw + (long)o * 4096;
    bf16* dst = out + (long)o * 4096;
#pragma unroll
    for (int k = 0; k < 4; k++)
        *(f32x4*)&t[(threadIdx.x + k * 256) * 4] = *(const f32x4*)&src[(threadIdx.x + k * 256) * 4];
    __syncthreads();
#pragma unroll
    for (int k = 0; k < 8; k++) {
        int d2 = 2 * (threadIdx.x + k * 256);
        int pi = ((d2 & 1023) << 2) | (d2 >> 10);
        bf16x2 h = { (bf16)t[pi], (bf16)t[pi + 4] };
        *(bf16x2*)&dst[d2] = h;
    }
}

// prologue: Wq T | Wkv T | Wout T | convw | casts
__global__ __launch_bounds__(256)
void prologue_kernel(const float* __restrict__ Wq, bf16* __restrict__ WqTb,
                     const float* __restrict__ Wkv, bf16* __restrict__ WkvTb,
                     const float* __restrict__ Wout, bf16* __restrict__ WoutTb,
                     const float* __restrict__ conv_w, bf16* __restrict__ convwTb,
                     const float* __restrict__ pe, bf16* __restrict__ peb,
                     const float* __restrict__ x, bf16* __restrict__ xb,
                     const float* __restrict__ mem, bf16* __restrict__ memb,
                     const float* __restrict__ cmem, bf16* __restrict__ cmemb,
                     float* __restrict__ xmirror)
{
    __shared__ float t[4096];
    int gid = blockIdx.x;
    if (gid < 1024) {
        transpose_body(gid & 31, gid >> 5, Wq, WqTb, 1024, 1024, t);
    } else if (gid < 3072) {
        int g = gid - 1024;
        transpose_body(g & 63, g >> 6, Wkv, WkvTb, 1024, 2048, t);
    } else if (gid < 4096) {
        int g = gid - 3072;
        transpose_body(g & 31, g >> 5, Wout, WoutTb, 1024, 1024, t);
    } else if (gid < 5120) {
        convw_body(gid - 4096, conv_w, convwTb, t);
    } else {
        int i0 = (gid - 5120) * 256 + threadIdx.x;
        const int n0 = 294912, n1 = 1048576, n2 = 1048576, n3 = 262144;
        for (int i = i0; i < n0 + n1 + n2 + n3; i += 2048 * 256) {
            const float* src; bf16* dst; int k = i; int seg;
            if (k < n0) { src = pe; dst = peb; seg = 0; }
            else if ((k -= n0) < n1) { src = x; dst = xb; seg = 1; }
            else if ((k -= n1) < n2) { src = mem; dst = memb; seg = 2; }
            else { k -= n2; src = cmem; dst = cmemb; seg = 3; }
            f32x4 f = reinterpret_cast<const f32x4*>(src)[k];
            bf16x4 h = { (bf16)f[0], (bf16)f[1], (bf16)f[2], (bf16)f[3] };
            reinterpret_cast<bf16x4*>(dst)[k] = h;
            if (seg == 1)
                __builtin_nontemporal_store(f, &reinterpret_cast<f32x4*>(xmirror)[k]);
        }
    }
}

__global__ __launch_bounds__(256)
void aux_reduce_kernel(const float* __restrict__ partials, float* __restrict__ out)
{
    int tid = threadIdx.x;
    __shared__ float wred[4];
    float s = 0.f;
    for (int i = tid; i < 512; i += 256) s += partials[i];
#pragma unroll
    for (int off = 32; off; off >>= 1) s += __shfl_xor(s, off, 64);
    if ((tid & 63) == 0) wred[tid >> 6] = s;
    __syncthreads();
    if (tid == 0) out[0] = (wred[0] + wred[1] + wred[2] + wred[3]) * (1.0f / 4194304.0f);
}

extern "C" void kernel_launch(void* const* d_in, const int* in_sizes, int n_in,
                              void* d_out, int out_size, void* d_ws, size_t ws_size,
                              hipStream_t stream)
{
    const float* x      = (const float*)d_in[0];
    const float* mem    = (const float*)d_in[1];
    const float* cmem   = (const float*)d_in[2];
    const float* pe     = (const float*)d_in[3];
    const float* Wq     = (const float*)d_in[4];
    const float* Wkv    = (const float*)d_in[5];
    const float* Wout   = (const float*)d_in[6];
    const float* bout   = (const float*)d_in[7];
    const float* conv_w = (const float*)d_in[8];
    const float* conv_b = (const float*)d_in[9];

    float* out_logits  = (float*)d_out;                 // 8*512*1024
    float* out_newmem  = out_logits + 4194304;          // 8*512*1024
    float* out_newcmem = out_newmem + 4194304;          // 8*128*1024
    float* out_aux     = out_newcmem + 1048576;         // 1
    float* out_weights = out_aux + 1;                   // 8*16*512*1152

    float* ws       = (float*)d_ws;
    float* partials = ws;                    // 4096 f
    float* pbuf     = partials + 4096;       // 4 * 1,048,576 f
    bf16* bws     = (bf16*)(pbuf + 4194304);
    bf16* WqTb    = bws;                     // 1,048,576
    bf16* WkvTb   = WqTb + 1048576;          // 2,097,152
    bf16* WoutTb  = WkvTb + 2097152;         // 1,048,576
    bf16* convwTb = WoutTb + 1048576;        // 4,194,304
    bf16* vTb     = convwTb + 4194304;       // 9,437,184
    bf16* cvT     = vTb + 9437184;           // 1,048,576
    bf16* qb      = cvT + 1048576;           // 4,194,304
    bf16* kb      = qb + 4194304;            // 9,437,184
    bf16* ckb     = kb + 9437184;            // 1,048,576
    bf16* peb     = ckb + 1048576;           // 1,179,648
    bf16* xb      = peb + 1179648;           // 4,194,304
    bf16* memb    = xb + 4194304;            // 4,194,304
    bf16* cmemb   = memb + 4194304;          // 1,048,576
    bf16* ncmemb  = cmemb + 1048576;         // 1,048,576
    bf16* oatb    = ncmemb + 1048576;        // 4,194,304

    dim3 blk(256);

    // merged prologue: weight transposes + convw cast + input casts
    prologue_kernel<<<dim3(7168), blk, 0, stream>>>(
        Wq, WqTb, Wkv, WkvTb, Wout, WoutTb, conv_w, convwTb,
        pe, peb, x, xb, mem, memb, cmem, cmemb, out_newmem);

    // Launch A: kv + q + conv split-K
    gemmA_kernel<<<dim3(1664), blk, 0, stream>>>(
        xb, memb, cmemb, WqTb, WkvTb, convwTb, qb, kb, vTb, pbuf);

    // reduce partials + bias -> new_cmem (fp32) + ncmemb (bf16)
    splitk_reduce<<<dim3(1024), blk, 0, stream>>>(pbuf, conv_b, out_newcmem, ncmemb);

    // ckv standalone (128 blocks)
    ckv_kernel<<<dim3(128), blk, 0, stream>>>(ncmemb, WkvTb, ckb, cvT);

    // fused attention (standalone)
    attn_fused16<<<dim3(4096), blk, 0, stream>>>(qb, kb, peb, vTb, out_weights, oatb);

    // Launch C: aux + logits
    logits_aux_kernel<<<dim3(768), blk, 0, stream>>>(
        qb, kb, ckb, vTb, cvT, partials, oatb, WoutTb, out_logits, bout);

    aux_reduce_kernel<<<dim3(1), blk, 0, stream>>>(partials, out_aux);
}

// Round 25
// 487.441 us; speedup vs baseline: 1.0074x; 1.0074x over previous
//
#include <hip/hip_runtime.h>
#include <cstdint>

// HEADS=16, DIM=1024, SEQ=512, MEM=512, CMEM=128, RATIO=4, DIM_H=64, b=8, kv_len=1152

typedef __bf16 bf16;
typedef __bf16 bf16x2 __attribute__((ext_vector_type(2)));
typedef __bf16 bf16x4 __attribute__((ext_vector_type(4)));
typedef __bf16 bf16x8 __attribute__((ext_vector_type(8)));
typedef float  f32x2  __attribute__((ext_vector_type(2)));
typedef float  f32x4  __attribute__((ext_vector_type(4)));

#define GLOAD_LDS16(g, l) \
    __builtin_amdgcn_global_load_lds((const __attribute__((address_space(1))) void*)(g), \
                                     (__attribute__((address_space(3))) void*)(l), 16, 0, 0)

// ---------------------------------------------------------------------------
// GEMM body: tile 128x128, BK=32, 4 waves, global_load_lds staging, XOR swizzle.
// ---------------------------------------------------------------------------
template<int AMODE, int EPI>
__device__ __forceinline__ void gemm_body(
    int bx, int by, int bz,
    const bf16* __restrict__ A, const bf16* __restrict__ B2,
    float* __restrict__ C, bf16* __restrict__ outB, bf16* __restrict__ vT,
    int N, int K, int lda, int ldbt, int ldc,
    const float* __restrict__ bias, int vrows,
    const bf16* __restrict__ gcmem, const bf16* __restrict__ gmem,
    const bf16* __restrict__ gx,
    bf16* As, bf16* Bs)
{
    int row0 = by * 128, col0 = bx * 128;
    int tid = threadIdx.x;
    int kofs = (EPI == 8) ? bz * K : 0;

    int lane = tid & 63, wid = tid >> 6;
    int wr = wid >> 1, wc = wid & 1;
    int fr = lane & 15, fq = lane >> 4;

    int srow = lane >> 2;
    int sc16 = (lane & 3) ^ ((lane >> 3) & 3);
    const bf16* aq[2];
    const bf16* bq[2];
    bf16* as_dst[2];
    bf16* bs_dst[2];
#pragma unroll
    for (int t = 0; t < 2; t++) {
        int gr = row0 + wid * 32 + t * 16 + srow;
        const bf16* ap;
        if (AMODE == 0) {
            ap = A + (long)gr * lda + kofs;
        } else {
            int bb = gr / 1152, rr = gr - bb * 1152;
            ap = (rr < 128) ? (gcmem + ((long)bb * 128 + rr) * 1024)
               : (rr < 640) ? (gmem + ((long)bb * 512 + (rr - 128)) * 1024)
                            : (gx   + ((long)bb * 512 + (rr - 640)) * 1024);
        }
        aq[t] = ap + sc16 * 8;
        int gc = col0 + wid * 32 + t * 16 + srow;
        bq[t] = B2 + (long)gc * ldbt + kofs + sc16 * 8;
        as_dst[t] = &As[(wid * 32 + t * 16) * 32];
        bs_dst[t] = &Bs[(wid * 32 + t * 16) * 32];
    }

    int sfq = (fq ^ ((fr >> 1) & 3)) * 8;

    f32x4 acc[4][4];
#pragma unroll
    for (int i = 0; i < 4; i++)
#pragma unroll
        for (int j = 0; j < 4; j++) acc[i][j] = (f32x4){0.f, 0.f, 0.f, 0.f};

    for (int k0 = 0; k0 < K; k0 += 32) {
#pragma unroll
        for (int t = 0; t < 2; t++) {
            GLOAD_LDS16(aq[t] + k0, as_dst[t]);
            GLOAD_LDS16(bq[t] + k0, bs_dst[t]);
        }
        __syncthreads();

        bf16x8 af[4], bfv[4];
#pragma unroll
        for (int i = 0; i < 4; i++)
            af[i] = *(const bf16x8*)&As[(wr * 64 + i * 16 + fr) * 32 + sfq];
#pragma unroll
        for (int j = 0; j < 4; j++)
            bfv[j] = *(const bf16x8*)&Bs[(wc * 64 + j * 16 + fr) * 32 + sfq];
#pragma unroll
        for (int i = 0; i < 4; i++)
#pragma unroll
            for (int j = 0; j < 4; j++)
                acc[i][j] = __builtin_amdgcn_mfma_f32_16x16x32_bf16(af[i], bfv[j], acc[i][j], 0, 0, 0);
        __syncthreads();
    }

#pragma unroll
    for (int i = 0; i < 4; i++) {
#pragma unroll
        for (int j = 0; j < 4; j++) {
#pragma unroll
            for (int g = 0; g < 4; g++) {
                int r = row0 + wr * 64 + i * 16 + fq * 4 + g;
                int c = col0 + wc * 64 + j * 16 + fr;
                float v = acc[i][j][g];
                if (EPI == 0) {
                    if (bias) v += bias[c];
                    C[(long)r * ldc + c] = v;
                } else if (EPI == 6) {
                    if (bias) v += bias[c];
                    __builtin_nontemporal_store(v, &C[(long)r * ldc + c]);
                } else if (EPI == 8) {
                    C[((long)bz << 20) + (long)r * 1024 + c] = v;
                } else if (EPI == 4) {
                    outB[(long)r * ldc + c] = (bf16)v;
                } else { // EPI == 5
                    if (c < 1024) {
                        outB[(long)r * 1024 + c] = (bf16)v;
                    } else {
                        int d = c - 1024; int hh = d >> 6; d &= 63;
                        int bb = r / vrows; int j2 = r - bb * vrows;
                        vT[(((long)(bb * 16 + hh)) * 64 + d) * vrows + j2] = (bf16)v;
                    }
                }
            }
        }
    }
}

// ---------------------------------------------------------------------------
// aux body (round-10 structure), shared carved from pool.
// ---------------------------------------------------------------------------
__device__ __forceinline__ void aux_body(
    int bx, int by,
    const bf16* __restrict__ qb, const bf16* __restrict__ kb,
    const bf16* __restrict__ ckb,
    const bf16* __restrict__ vTb, const bf16* __restrict__ cvT,
    float* __restrict__ partials,
    bf16* qs, bf16* upool, bf16* vt, float* wred)
{
    int z = by;
    int b = z >> 4, h = z & 15;
    int r0 = bx * 128;
    int tid = threadIdx.x;
    int lane = tid & 63, wid = tid >> 6;
    int fr = lane & 15, fq = lane >> 4;

#pragma unroll
    for (int t = 0; t < 4; t++) {
        int e = tid + 256 * t; int rr = e >> 3, c8 = (e & 7) * 8;
        *(bf16x8*)&qs[rr * 72 + c8] = *(const bf16x8*)&qb[((long)(b * 512 + r0 + rr)) * 1024 + h * 64 + c8];
    }

    float o1[2][4][4];
    f32x4 oaccv[2][4];
    float mrow[2][4], lrow[2][4];
    f32x4 sacc[2][8];
    float local = 0.f;

    for (int pass = 0; pass < 2; pass++) {
#pragma unroll
        for (int i = 0; i < 2; i++)
#pragma unroll
            for (int g = 0; g < 4; g++) { mrow[i][g] = -3.4e38f; lrow[i][g] = 0.f; }
#pragma unroll
        for (int i = 0; i < 2; i++)
#pragma unroll
            for (int jd = 0; jd < 4; jd++) oaccv[i][jd] = (f32x4){0.f, 0.f, 0.f, 0.f};

        int nchunk = pass ? 1 : 4;
        for (int jt = 0; jt < nchunk; jt++) {
            __syncthreads();
            if (pass == 0) {
                long base = (long)(b * 1152 + 128 + jt * 128);
#pragma unroll
                for (int t = 0; t < 4; t++) {
                    int e = tid + 256 * t; int j = e >> 3, c8 = (e & 7) * 8;
                    *(bf16x8*)&upool[j * 72 + c8] = *(const bf16x8*)&kb[(base + j) * 1024 + h * 64 + c8];
                }
#pragma unroll
                for (int t = 0; t < 4; t++) {
                    int e = tid + 256 * t; int d = e >> 4, j8 = (e & 15) * 8;
                    *(bf16x8*)&vt[d * 136 + j8] =
                        *(const bf16x8*)&vTb[((long)z * 64 + d) * 1152 + 128 + jt * 128 + j8];
                }
            } else {
#pragma unroll
                for (int t = 0; t < 4; t++) {
                    int e = tid + 256 * t; int j = e >> 3, c8 = (e & 7) * 8;
                    *(bf16x8*)&upool[j * 72 + c8] = *(const bf16x8*)&ckb[((long)(b * 128 + j)) * 1024 + h * 64 + c8];
                }
#pragma unroll
                for (int t = 0; t < 4; t++) {
                    int e = tid + 256 * t; int d = e >> 4, j8 = (e & 15) * 8;
                    *(bf16x8*)&vt[d * 136 + j8] = *(const bf16x8*)&cvT[((long)z * 64 + d) * 128 + j8];
                }
            }
            __syncthreads();

#pragma unroll
            for (int i = 0; i < 2; i++)
#pragma unroll
                for (int j = 0; j < 8; j++) sacc[i][j] = (f32x4){0.f, 0.f, 0.f, 0.f};
#pragma unroll
            for (int s = 0; s < 2; s++) {
                bf16x8 af[2], bfv[8];
#pragma unroll
                for (int i = 0; i < 2; i++)
                    af[i] = *(const bf16x8*)&qs[(wid * 32 + i * 16 + fr) * 72 + s * 32 + fq * 8];
#pragma unroll
                for (int j = 0; j < 8; j++)
                    bfv[j] = *(const bf16x8*)&upool[(j * 16 + fr) * 72 + s * 32 + fq * 8];
#pragma unroll
                for (int i = 0; i < 2; i++)
#pragma unroll
                    for (int j = 0; j < 8; j++)
                        sacc[i][j] = __builtin_amdgcn_mfma_f32_16x16x32_bf16(af[i], bfv[j], sacc[i][j], 0, 0, 0);
            }
            __syncthreads();

#pragma unroll
            for (int i = 0; i < 2; i++) {
#pragma unroll
                for (int g = 0; g < 4; g++) {
                    float mx = -3.4e38f;
#pragma unroll
                    for (int j = 0; j < 8; j++) mx = fmaxf(mx, sacc[i][j][g]);
                    mx *= 0.125f;
#pragma unroll
                    for (int msk = 1; msk <= 8; msk <<= 1) mx = fmaxf(mx, __shfl_xor(mx, msk, 64));
                    float mnew = fmaxf(mrow[i][g], mx);
                    float alpha = __expf(mrow[i][g] - mnew);
                    mrow[i][g] = mnew;
                    float sum = 0.f;
                    int prow = (wid * 32 + i * 16 + fq * 4 + g) * 136;
#pragma unroll
                    for (int j = 0; j < 8; j++) {
                        float p = __expf(sacc[i][j][g] * 0.125f - mnew);
                        sum += p;
                        upool[prow + j * 16 + fr] = (bf16)p;
                    }
#pragma unroll
                    for (int msk = 1; msk <= 8; msk <<= 1) sum += __shfl_xor(sum, msk, 16);
                    lrow[i][g] = lrow[i][g] * alpha + sum;
#pragma unroll
                    for (int jd = 0; jd < 4; jd++) oaccv[i][jd][g] *= alpha;
                }
            }
            __syncthreads();

#pragma unroll
            for (int s2 = 0; s2 < 4; s2++) {
                bf16x8 pa[2], vb[4];
#pragma unroll
                for (int i = 0; i < 2; i++)
                    pa[i] = *(const bf16x8*)&upool[(wid * 32 + i * 16 + fr) * 136 + s2 * 32 + fq * 8];
#pragma unroll
                for (int jd = 0; jd < 4; jd++)
                    vb[jd] = *(const bf16x8*)&vt[(jd * 16 + fr) * 136 + s2 * 32 + fq * 8];
#pragma unroll
                for (int i = 0; i < 2; i++)
#pragma unroll
                    for (int jd = 0; jd < 4; jd++)
                        oaccv[i][jd] = __builtin_amdgcn_mfma_f32_16x16x32_bf16(pa[i], vb[jd], oaccv[i][jd], 0, 0, 0);
            }
        }

        if (pass == 0) {
#pragma unroll
            for (int i = 0; i < 2; i++)
#pragma unroll
                for (int jd = 0; jd < 4; jd++)
#pragma unroll
                    for (int g = 0; g < 4; g++)
                        o1[i][jd][g] = oaccv[i][jd][g] / lrow[i][g];
        } else {
#pragma unroll
            for (int i = 0; i < 2; i++)
#pragma unroll
                for (int jd = 0; jd < 4; jd++)
#pragma unroll
                    for (int g = 0; g < 4; g++) {
                        float dd = o1[i][jd][g] - oaccv[i][jd][g] / lrow[i][g];
                        local += dd * dd;
                    }
        }
    }

#pragma unroll
    for (int off = 32; off; off >>= 1) local += __shfl_xor(local, off, 64);
    if (lane == 0) wred[wid] = local;
    __syncthreads();
    if (tid == 0)
        partials[(long)by * 4 + bx] = wred[0] + wred[1] + wred[2] + wred[3];
}

// ---------------------------------------------------------------------------
// Launch A: kv (0..1151) | q (1152..1407) | conv split-K (1408..1663)
// ---------------------------------------------------------------------------
__global__ __launch_bounds__(256)
void gemmA_kernel(const bf16* __restrict__ xb, const bf16* __restrict__ memb,
                  const bf16* __restrict__ cmemb,
                  const bf16* __restrict__ WqTb, const bf16* __restrict__ WkvTb,
                  const bf16* __restrict__ convwTb,
                  bf16* __restrict__ qb, bf16* __restrict__ kb, bf16* __restrict__ vTb,
                  float* __restrict__ pbuf)
{
    __shared__ bf16 As[128 * 32];
    __shared__ bf16 Bs[128 * 32];
    int gid = blockIdx.x;
    if (gid < 1152) {
        gemm_body<1, 5>(gid % 16, gid / 16, 0, nullptr, WkvTb, nullptr, kb, vTb,
                        2048, 1024, 1024, 1024, 2048, nullptr, 1152,
                        cmemb, memb, xb, As, Bs);
    } else if (gid < 1408) {
        int g = gid - 1152;
        gemm_body<0, 4>(g % 8, g / 8, 0, xb, WqTb, nullptr, qb, nullptr,
                        1024, 1024, 1024, 1024, 1024, nullptr, 0,
                        nullptr, nullptr, nullptr, As, Bs);
    } else {
        int g = gid - 1408;
        gemm_body<0, 8>(g % 8, (g / 8) % 8, g / 64, memb, convwTb, pbuf, nullptr, nullptr,
                        1024, 1024, 4096, 4096, 1024, nullptr, 0,
                        nullptr, nullptr, nullptr, As, Bs);
    }
}

// ckv standalone: 128 blocks
__global__ __launch_bounds__(256)
void ckv_kernel(const bf16* __restrict__ ncmemb, const bf16* __restrict__ WkvTb,
                bf16* __restrict__ ckb, bf16* __restrict__ cvT)
{
    __shared__ bf16 As[128 * 32];
    __shared__ bf16 Bs[128 * 32];
    gemm_body<0, 5>(blockIdx.x % 16, blockIdx.x / 16, 0, ncmemb, WkvTb, nullptr, ckb, cvT,
                    2048, 1024, 1024, 1024, 2048, nullptr, 128,
                    nullptr, nullptr, nullptr, As, Bs);
}

// ---------------------------------------------------------------------------
// Fused attention (round-10 best, standalone)
// ---------------------------------------------------------------------------
#define SSTR 1164

__global__ __launch_bounds__(256)
void attn_fused16(const bf16* __restrict__ qb, const bf16* __restrict__ kb,
                  const bf16* __restrict__ peb, const bf16* __restrict__ vTb,
                  float* __restrict__ weights, bf16* __restrict__ oatb)
{
    int bid = blockIdx.x;
    int w = (bid & 7) * 512 + (bid >> 3);
    int z = w >> 5;
    int b = z >> 4, h = z & 15;
    int r0 = (w & 31) * 16;
    int tid = threadIdx.x;
    int lane = tid & 63, wid = tid >> 6;
    int fr = lane & 15, fq = lane >> 4;

    __shared__ bf16 S[16 * SSTR];

    bf16x8 afr[2];
#pragma unroll
    for (int ks = 0; ks < 2; ks++)
        afr[ks] = *(const bf16x8*)&qb[((long)(b * 512 + r0 + fr)) * 1024 + h * 64 + ks * 32 + fq * 8];

#pragma unroll 3
    for (int ch = 0; ch < 9; ch++) {
        int c0 = ch * 128;
        int jb0 = c0 + 496 - r0 + 32 * wid;

        f32x4 p[3];
#pragma unroll
        for (int ct = 0; ct < 3; ct++) {
            f32x4 a = (f32x4){0.f, 0.f, 0.f, 0.f};
            int j = jb0 + ct * 16 + fr;
            bool ok = (j < 1152);
#pragma unroll
            for (int ks = 0; ks < 2; ks++) {
                bf16x8 bv = {};
                if (ok) bv = *(const bf16x8*)&peb[((long)(h * 1152 + j)) * 64 + ks * 32 + fq * 8];
                a = __builtin_amdgcn_mfma_f32_16x16x32_bf16(afr[ks], bv, a, 0, 0, 0);
            }
            p[ct] = a;
        }

#pragma unroll
        for (int tt = 0; tt < 2; tt++) {
            int cc = 32 * wid + 16 * tt + fr;
            f32x4 a = (f32x4){0.f, 0.f, 0.f, 0.f};
            long krow = (long)(b * 1152 + c0 + cc);
#pragma unroll
            for (int ks = 0; ks < 2; ks++) {
                bf16x8 bv = *(const bf16x8*)&kb[krow * 1024 + h * 64 + ks * 32 + fq * 8];
                a = __builtin_amdgcn_mfma_f32_16x16x32_bf16(afr[ks], bv, a, 0, 0, 0);
            }
#pragma unroll
            for (int g = 0; g < 4; g++) {
                int rr = fq * 4 + g;
                int uu = fr + 15 - rr;
                int src = (uu & 15) | (fq << 4);
                float s0 = __shfl(p[tt][g], src, 64);
                float s1 = __shfl(p[tt + 1][g], src, 64);
                float pv = (uu < 16) ? s0 : s1;
                S[rr * SSTR + c0 + cc] = (bf16)(0.125f * (a[g] + pv));
            }
        }
    }
    __syncthreads();

    for (int rw = 0; rw < 4; rw++) {
        int row = wid * 4 + rw;
        bf16* Srow = &S[row * SSTR];
        bf16x8 v0 = *(const bf16x8*)&Srow[lane * 8];
        bf16x8 v1 = *(const bf16x8*)&Srow[512 + lane * 8];
        bf16x2 v2 = *(const bf16x2*)&Srow[1024 + lane * 2];
        float e[18];
#pragma unroll
        for (int j = 0; j < 8; j++) { e[j] = (float)v0[j]; e[8 + j] = (float)v1[j]; }
        e[16] = (float)v2[0]; e[17] = (float)v2[1];

        float m = e[0];
#pragma unroll
        for (int k = 1; k < 18; k++) m = fmaxf(m, e[k]);
#pragma unroll
        for (int off = 32; off; off >>= 1) m = fmaxf(m, __shfl_xor(m, off, 64));
        float sm = 0.f;
#pragma unroll
        for (int k = 0; k < 18; k++) { e[k] = __expf(e[k] - m); sm += e[k]; }
#pragma unroll
        for (int off = 32; off; off >>= 1) sm += __shfl_xor(sm, off, 64);
        float inv = 1.f / sm;

        bf16x8 w0, w1; bf16x2 w2;
#pragma unroll
        for (int j = 0; j < 8; j++) { w0[j] = (bf16)(e[j] * inv); w1[j] = (bf16)(e[8 + j] * inv); }
        w2[0] = (bf16)(e[16] * inv); w2[1] = (bf16)(e[17] * inv);
        *(bf16x8*)&Srow[lane * 8] = w0;
        *(bf16x8*)&Srow[512 + lane * 8] = w1;
        *(bf16x2*)&Srow[1024 + lane * 2] = w2;
    }
    __syncthreads();

    f32x4 oacc = (f32x4){0.f, 0.f, 0.f, 0.f};
    int dt = wid;
    for (int ch = 0; ch < 9; ch++) {
        int c0 = ch * 128;
#pragma unroll
        for (int ks = 0; ks < 4; ks++) {
            bf16x8 pa = *(const bf16x8*)&S[fr * SSTR + c0 + ks * 32 + fq * 8];
            bf16x8 vb = *(const bf16x8*)&vTb[((long)z * 64 + dt * 16 + fr) * 1152 + c0 + ks * 32 + fq * 8];
            oacc = __builtin_amdgcn_mfma_f32_16x16x32_bf16(pa, vb, oacc, 0, 0, 0);
        }
    }
#pragma unroll
    for (int g = 0; g < 4; g++)
        oatb[((long)(b * 512 + r0 + fq * 4 + g)) * 1024 + h * 64 + dt * 16 + fr] = (bf16)oacc[g];

    for (int rw = 0; rw < 4; rw++) {
        int row = wid * 4 + rw;
        const bf16* Srow = &S[row * SSTR];
        long wbase = ((long)z * 512 + r0 + row) * 1152;
        bf16x8 v0 = *(const bf16x8*)&Srow[lane * 8];
        bf16x8 v1 = *(const bf16x8*)&Srow[512 + lane * 8];
        bf16x2 v2 = *(const bf16x2*)&Srow[1024 + lane * 2];
        f32x4 a0 = { (float)v0[0], (float)v0[1], (float)v0[2], (float)v0[3] };
        f32x4 a1 = { (float)v0[4], (float)v0[5], (float)v0[6], (float)v0[7] };
        f32x4 b0 = { (float)v1[0], (float)v1[1], (float)v1[2], (float)v1[3] };
        f32x4 b1 = { (float)v1[4], (float)v1[5], (float)v1[6], (float)v1[7] };
        f32x2 c0 = { (float)v2[0], (float)v2[1] };
        __builtin_nontemporal_store(a0, (f32x4*)&weights[wbase + lane * 8]);
        __builtin_nontemporal_store(a1, (f32x4*)&weights[wbase + lane * 8 + 4]);
        __builtin_nontemporal_store(b0, (f32x4*)&weights[wbase + 512 + lane * 8]);
        __builtin_nontemporal_store(b1, (f32x4*)&weights[wbase + 512 + lane * 8 + 4]);
        __builtin_nontemporal_store(c0, (f32x2*)&weights[wbase + 1024 + lane * 2]);
    }
}

// Launch C: aux (0..511) | logits (512..767)
__global__ __launch_bounds__(256)
void logits_aux_kernel(const bf16* __restrict__ qb, const bf16* __restrict__ kb,
                       const bf16* __restrict__ ckb,
                       const bf16* __restrict__ vTb, const bf16* __restrict__ cvT,
                       float* __restrict__ partials,
                       const bf16* __restrict__ oatb, const bf16* __restrict__ WoutTb,
                       float* __restrict__ out_logits, const float* __restrict__ bout)
{
    __shared__ bf16 pool[35328];   // qs 9216 | upool 17408 | vt 8704
    __shared__ float wred[4];
    int gid = blockIdx.x;
    if (gid < 512) {
        aux_body(gid % 4, gid / 4, qb, kb, ckb, vTb, cvT, partials,
                 pool, pool + 9216, pool + 26624, wred);
    } else {
        int g = gid - 512;
        gemm_body<0, 6>(g % 8, g / 8, 0, oatb, WoutTb, out_logits, nullptr, nullptr,
                        1024, 1024, 1024, 1024, 1024, bout, 0,
                        nullptr, nullptr, nullptr, pool, pool + 4096);
    }
}

// split-K reduce
__global__ __launch_bounds__(256)
void splitk_reduce(const float* __restrict__ pbuf, const float* __restrict__ bias,
                   float* __restrict__ outF, bf16* __restrict__ outB)
{
    int i = blockIdx.x * 256 + threadIdx.x;
    f32x4 s = reinterpret_cast<const f32x4*>(pbuf)[i];
#pragma unroll
    for (int k = 1; k < 4; k++) {
        f32x4 t = reinterpret_cast<const f32x4*>(pbuf + (long)k * 1048576)[i];
        s[0] += t[0]; s[1] += t[1]; s[2] += t[2]; s[3] += t[3];
    }
    int col4 = (i << 2) & 1023;
    f32x4 bv = *(const f32x4*)&bias[col4];
    s[0] += bv[0]; s[1] += bv[1]; s[2] += bv[2]; s[3] += bv[3];
    reinterpret_cast<f32x4*>(outF)[i] = s;
    bf16x4 h = { (bf16)s[0], (bf16)s[1], (bf16)s[2], (bf16)s[3] };
    reinterpret_cast<bf16x4*>(outB)[i] = h;
}

// ---------------------------------------------------------------------------
// Prologue bodies
// ---------------------------------------------------------------------------
__device__ __forceinline__ void transpose_body(
    int bx, int by, const float* __restrict__ in, bf16* __restrict__ out,
    int R, int C, float* t /* 32*33 floats */)
{
    int c0 = bx * 32, r0 = by * 32;
    int tx = threadIdx.x & 31, ty = threadIdx.x >> 5;
#pragma unroll
    for (int i = 0; i < 32; i += 8)
        t[(ty + i) * 33 + tx] = in[(long)(r0 + ty + i) * C + c0 + tx];
    __syncthreads();
#pragma unroll
    for (int i = 0; i < 32; i += 8)
        out[(long)(c0 + ty + i) * R + r0 + tx] = (bf16)t[tx * 33 + ty + i];
}

__device__ __forceinline__ void convw_body(
    int o, const float* __restrict__ cw, bf16* __restrict__ out, float* t /*4096*/)
{
    const float* src = cw + (long)o * 4096;
    bf16* dst = out + (long)o * 4096;
#pragma unroll
    for (int k = 0; k < 4; k++)
        *(f32x4*)&t[(threadIdx.x + k * 256) * 4] = *(const f32x4*)&src[(threadIdx.x + k * 256) * 4];
    __syncthreads();
#pragma unroll
    for (int k = 0; k < 8; k++) {
        int d2 = 2 * (threadIdx.x + k * 256);
        int pi = ((d2 & 1023) << 2) | (d2 >> 10);
        bf16x2 h = { (bf16)t[pi], (bf16)t[pi + 4] };
        *(bf16x2*)&dst[d2] = h;
    }
}

// prologue: Wq T | Wkv T | Wout T | convw | casts
__global__ __launch_bounds__(256)
void prologue_kernel(const float* __restrict__ Wq, bf16* __restrict__ WqTb,
                     const float* __restrict__ Wkv, bf16* __restrict__ WkvTb,
                     const float* __restrict__ Wout, bf16* __restrict__ WoutTb,
                     const float* __restrict__ conv_w, bf16* __restrict__ convwTb,
                     const float* __restrict__ pe, bf16* __restrict__ peb,
                     const float* __restrict__ x, bf16* __restrict__ xb,
                     const float* __restrict__ mem, bf16* __restrict__ memb,
                     const float* __restrict__ cmem, bf16* __restrict__ cmemb,
                     float* __restrict__ xmirror)
{
    __shared__ float t[4096];
    int gid = blockIdx.x;
    if (gid < 1024) {
        transpose_body(gid & 31, gid >> 5, Wq, WqTb, 1024, 1024, t);
    } else if (gid < 3072) {
        int g = gid - 1024;
        transpose_body(g & 63, g >> 6, Wkv, WkvTb, 1024, 2048, t);
    } else if (gid < 4096) {
        int g = gid - 3072;
        transpose_body(g & 31, g >> 5, Wout, WoutTb, 1024, 1024, t);
    } else if (gid < 5120) {
        convw_body(gid - 4096, conv_w, convwTb, t);
    } else {
        int i0 = (gid - 5120) * 256 + threadIdx.x;
        const int n0 = 294912, n1 = 1048576, n2 = 1048576, n3 = 262144;
        for (int i = i0; i < n0 + n1 + n2 + n3; i += 2048 * 256) {
            const float* src; bf16* dst; int k = i; int seg;
            if (k < n0) { src = pe; dst = peb; seg = 0; }
            else if ((k -= n0) < n1) { src = x; dst = xb; seg = 1; }
            else if ((k -= n1) < n2) { src = mem; dst = memb; seg = 2; }
            else { k -= n2; src = cmem; dst = cmemb; seg = 3; }
            f32x4 f = reinterpret_cast<const f32x4*>(src)[k];
            bf16x4 h = { (bf16)f[0], (bf16)f[1], (bf16)f[2], (bf16)f[3] };
            reinterpret_cast<bf16x4*>(dst)[k] = h;
            if (seg == 1)
                __builtin_nontemporal_store(f, &reinterpret_cast<f32x4*>(xmirror)[k]);
        }
    }
}

__global__ __launch_bounds__(256)
void aux_reduce_kernel(const float* __restrict__ partials, float* __restrict__ out)
{
    int tid = threadIdx.x;
    __shared__ float wred[4];
    float s = 0.f;
    for (int i = tid; i < 512; i += 256) s += partials[i];
#pragma unroll
    for (int off = 32; off; off >>= 1) s += __shfl_xor(s, off, 64);
    if ((tid & 63) == 0) wred[tid >> 6] = s;
    __syncthreads();
    if (tid == 0) out[0] = (wred[0] + wred[1] + wred[2] + wred[3]) * (1.0f / 4194304.0f);
}

extern "C" void kernel_launch(void* const* d_in, const int* in_sizes, int n_in,
                              void* d_out, int out_size, void* d_ws, size_t ws_size,
                              hipStream_t stream)
{
    const float* x      = (const float*)d_in[0];
    const float* mem    = (const float*)d_in[1];
    const float* cmem   = (const float*)d_in[2];
    const float* pe     = (const float*)d_in[3];
    const float* Wq     = (const float*)d_in[4];
    const float* Wkv    = (const float*)d_in[5];
    const float* Wout   = (const float*)d_in[6];
    const float* bout   = (const float*)d_in[7];
    const float* conv_w = (const float*)d_in[8];
    const float* conv_b = (const float*)d_in[9];

    float* out_logits  = (float*)d_out;                 // 8*512*1024
    float* out_newmem  = out_logits + 4194304;          // 8*512*1024
    float* out_newcmem = out_newmem + 4194304;          // 8*128*1024
    float* out_aux     = out_newcmem + 1048576;         // 1
    float* out_weights = out_aux + 1;                   // 8*16*512*1152

    float* ws       = (float*)d_ws;
    float* partials = ws;                    // 4096 f
    float* pbuf     = partials + 4096;       // 4 * 1,048,576 f
    bf16* bws     = (bf16*)(pbuf + 4194304);
    bf16* WqTb    = bws;                     // 1,048,576
    bf16* WkvTb   = WqTb + 1048576;          // 2,097,152
    bf16* WoutTb  = WkvTb + 2097152;         // 1,048,576
    bf16* convwTb = WoutTb + 1048576;        // 4,194,304
    bf16* vTb     = convwTb + 4194304;       // 9,437,184
    bf16* cvT     = vTb + 9437184;           // 1,048,576
    bf16* qb      = cvT + 1048576;           // 4,194,304
    bf16* kb      = qb + 4194304;            // 9,437,184
    bf16* ckb     = kb + 9437184;            // 1,048,576
    bf16* peb     = ckb + 1048576;           // 1,179,648
    bf16* xb      = peb + 1179648;           // 4,194,304
    bf16* memb    = xb + 4194304;            // 4,194,304
    bf16* cmemb   = memb + 4194304;          // 1,048,576
    bf16* ncmemb  = cmemb + 1048576;         // 1,048,576
    bf16* oatb    = ncmemb + 1048576;        // 4,194,304

    dim3 blk(256);

    // merged prologue: weight transposes + convw cast + input casts
    prologue_kernel<<<dim3(7168), blk, 0, stream>>>(
        Wq, WqTb, Wkv, WkvTb, Wout, WoutTb, conv_w, convwTb,
        pe, peb, x, xb, mem, memb, cmem, cmemb, out_newmem);

    // Launch A: kv + q + conv split-K
    gemmA_kernel<<<dim3(1664), blk, 0, stream>>>(
        xb, memb, cmemb, WqTb, WkvTb, convwTb, qb, kb, vTb, pbuf);

    // reduce partials + bias -> new_cmem (fp32) + ncmemb (bf16)
    splitk_reduce<<<dim3(1024), blk, 0, stream>>>(pbuf, conv_b, out_newcmem, ncmemb);

    // ckv standalone (128 blocks)
    ckv_kernel<<<dim3(128), blk, 0, stream>>>(ncmemb, WkvTb, ckb, cvT);

    // fused attention (standalone, 52 VGPR)
    attn_fused16<<<dim3(4096), blk, 0, stream>>>(qb, kb, peb, vTb, out_weights, oatb);

    // Launch C: aux + logits
    logits_aux_kernel<<<dim3(768), blk, 0, stream>>>(
        qb, kb, ckb, vTb, cvT, partials, oatb, WoutTb, out_logits, bout);

    aux_reduce_kernel<<<dim3(1), blk, 0, stream>>>(partials, out_aux);
}

// Round 26
// 487.290 us; speedup vs baseline: 1.0077x; 1.0003x over previous
//
#include <hip/hip_runtime.h>
#include <cstdint>

// HEADS=16, DIM=1024, SEQ=512, MEM=512, CMEM=128, RATIO=4, DIM_H=64, b=8, kv_len=1152

typedef __bf16 bf16;
typedef __bf16 bf16x2 __attribute__((ext_vector_type(2)));
typedef __bf16 bf16x4 __attribute__((ext_vector_type(4)));
typedef __bf16 bf16x8 __attribute__((ext_vector_type(8)));
typedef float  f32x2  __attribute__((ext_vector_type(2)));
typedef float  f32x4  __attribute__((ext_vector_type(4)));

#define GLOAD_LDS16(g, l) \
    __builtin_amdgcn_global_load_lds((const __attribute__((address_space(1))) void*)(g), \
                                     (__attribute__((address_space(3))) void*)(l), 16, 0, 0)

// ---------------------------------------------------------------------------
// GEMM body: tile 128x128, BK=32, 4 waves, global_load_lds staging, XOR swizzle.
// ---------------------------------------------------------------------------
template<int AMODE, int EPI>
__device__ __forceinline__ void gemm_body(
    int bx, int by, int bz,
    const bf16* __restrict__ A, const bf16* __restrict__ B2,
    float* __restrict__ C, bf16* __restrict__ outB, bf16* __restrict__ vT,
    int N, int K, int lda, int ldbt, int ldc,
    const float* __restrict__ bias, int vrows,
    const bf16* __restrict__ gcmem, const bf16* __restrict__ gmem,
    const bf16* __restrict__ gx,
    bf16* As, bf16* Bs)
{
    int row0 = by * 128, col0 = bx * 128;
    int tid = threadIdx.x;
    int kofs = (EPI == 8) ? bz * K : 0;

    int lane = tid & 63, wid = tid >> 6;
    int wr = wid >> 1, wc = wid & 1;
    int fr = lane & 15, fq = lane >> 4;

    int srow = lane >> 2;
    int sc16 = (lane & 3) ^ ((lane >> 3) & 3);
    const bf16* aq[2];
    const bf16* bq[2];
    bf16* as_dst[2];
    bf16* bs_dst[2];
#pragma unroll
    for (int t = 0; t < 2; t++) {
        int gr = row0 + wid * 32 + t * 16 + srow;
        const bf16* ap;
        if (AMODE == 0) {
            ap = A + (long)gr * lda + kofs;
        } else {
            int bb = gr / 1152, rr = gr - bb * 1152;
            ap = (rr < 128) ? (gcmem + ((long)bb * 128 + rr) * 1024)
               : (rr < 640) ? (gmem + ((long)bb * 512 + (rr - 128)) * 1024)
                            : (gx   + ((long)bb * 512 + (rr - 640)) * 1024);
        }
        aq[t] = ap + sc16 * 8;
        int gc = col0 + wid * 32 + t * 16 + srow;
        bq[t] = B2 + (long)gc * ldbt + kofs + sc16 * 8;
        as_dst[t] = &As[(wid * 32 + t * 16) * 32];
        bs_dst[t] = &Bs[(wid * 32 + t * 16) * 32];
    }

    int sfq = (fq ^ ((fr >> 1) & 3)) * 8;

    f32x4 acc[4][4];
#pragma unroll
    for (int i = 0; i < 4; i++)
#pragma unroll
        for (int j = 0; j < 4; j++) acc[i][j] = (f32x4){0.f, 0.f, 0.f, 0.f};

    for (int k0 = 0; k0 < K; k0 += 32) {
#pragma unroll
        for (int t = 0; t < 2; t++) {
            GLOAD_LDS16(aq[t] + k0, as_dst[t]);
            GLOAD_LDS16(bq[t] + k0, bs_dst[t]);
        }
        __syncthreads();

        bf16x8 af[4], bfv[4];
#pragma unroll
        for (int i = 0; i < 4; i++)
            af[i] = *(const bf16x8*)&As[(wr * 64 + i * 16 + fr) * 32 + sfq];
#pragma unroll
        for (int j = 0; j < 4; j++)
            bfv[j] = *(const bf16x8*)&Bs[(wc * 64 + j * 16 + fr) * 32 + sfq];
#pragma unroll
        for (int i = 0; i < 4; i++)
#pragma unroll
            for (int j = 0; j < 4; j++)
                acc[i][j] = __builtin_amdgcn_mfma_f32_16x16x32_bf16(af[i], bfv[j], acc[i][j], 0, 0, 0);
        __syncthreads();
    }

#pragma unroll
    for (int i = 0; i < 4; i++) {
#pragma unroll
        for (int j = 0; j < 4; j++) {
#pragma unroll
            for (int g = 0; g < 4; g++) {
                int r = row0 + wr * 64 + i * 16 + fq * 4 + g;
                int c = col0 + wc * 64 + j * 16 + fr;
                float v = acc[i][j][g];
                if (EPI == 0) {
                    if (bias) v += bias[c];
                    C[(long)r * ldc + c] = v;
                } else if (EPI == 6) {
                    if (bias) v += bias[c];
                    __builtin_nontemporal_store(v, &C[(long)r * ldc + c]);
                } else if (EPI == 8) {
                    C[((long)bz << 20) + (long)r * 1024 + c] = v;
                } else if (EPI == 4) {
                    outB[(long)r * ldc + c] = (bf16)v;
                } else { // EPI == 5
                    if (c < 1024) {
                        outB[(long)r * 1024 + c] = (bf16)v;
                    } else {
                        int d = c - 1024; int hh = d >> 6; d &= 63;
                        int bb = r / vrows; int j2 = r - bb * vrows;
                        vT[(((long)(bb * 16 + hh)) * 64 + d) * vrows + j2] = (bf16)v;
                    }
                }
            }
        }
    }
}

// ---------------------------------------------------------------------------
// aux body (round-10 structure), shared carved from pool.
// ---------------------------------------------------------------------------
__device__ __forceinline__ void aux_body(
    int bx, int by,
    const bf16* __restrict__ qb, const bf16* __restrict__ kb,
    const bf16* __restrict__ ckb,
    const bf16* __restrict__ vTb, const bf16* __restrict__ cvT,
    float* __restrict__ partials,
    bf16* qs, bf16* upool, bf16* vt, float* wred)
{
    int z = by;
    int b = z >> 4, h = z & 15;
    int r0 = bx * 128;
    int tid = threadIdx.x;
    int lane = tid & 63, wid = tid >> 6;
    int fr = lane & 15, fq = lane >> 4;

#pragma unroll
    for (int t = 0; t < 4; t++) {
        int e = tid + 256 * t; int rr = e >> 3, c8 = (e & 7) * 8;
        *(bf16x8*)&qs[rr * 72 + c8] = *(const bf16x8*)&qb[((long)(b * 512 + r0 + rr)) * 1024 + h * 64 + c8];
    }

    float o1[2][4][4];
    f32x4 oaccv[2][4];
    float mrow[2][4], lrow[2][4];
    f32x4 sacc[2][8];
    float local = 0.f;

    for (int pass = 0; pass < 2; pass++) {
#pragma unroll
        for (int i = 0; i < 2; i++)
#pragma unroll
            for (int g = 0; g < 4; g++) { mrow[i][g] = -3.4e38f; lrow[i][g] = 0.f; }
#pragma unroll
        for (int i = 0; i < 2; i++)
#pragma unroll
            for (int jd = 0; jd < 4; jd++) oaccv[i][jd] = (f32x4){0.f, 0.f, 0.f, 0.f};

        int nchunk = pass ? 1 : 4;
        for (int jt = 0; jt < nchunk; jt++) {
            __syncthreads();
            if (pass == 0) {
                long base = (long)(b * 1152 + 128 + jt * 128);
#pragma unroll
                for (int t = 0; t < 4; t++) {
                    int e = tid + 256 * t; int j = e >> 3, c8 = (e & 7) * 8;
                    *(bf16x8*)&upool[j * 72 + c8] = *(const bf16x8*)&kb[(base + j) * 1024 + h * 64 + c8];
                }
#pragma unroll
                for (int t = 0; t < 4; t++) {
                    int e = tid + 256 * t; int d = e >> 4, j8 = (e & 15) * 8;
                    *(bf16x8*)&vt[d * 136 + j8] =
                        *(const bf16x8*)&vTb[((long)z * 64 + d) * 1152 + 128 + jt * 128 + j8];
                }
            } else {
#pragma unroll
                for (int t = 0; t < 4; t++) {
                    int e = tid + 256 * t; int j = e >> 3, c8 = (e & 7) * 8;
                    *(bf16x8*)&upool[j * 72 + c8] = *(const bf16x8*)&ckb[((long)(b * 128 + j)) * 1024 + h * 64 + c8];
                }
#pragma unroll
                for (int t = 0; t < 4; t++) {
                    int e = tid + 256 * t; int d = e >> 4, j8 = (e & 15) * 8;
                    *(bf16x8*)&vt[d * 136 + j8] = *(const bf16x8*)&cvT[((long)z * 64 + d) * 128 + j8];
                }
            }
            __syncthreads();

#pragma unroll
            for (int i = 0; i < 2; i++)
#pragma unroll
                for (int j = 0; j < 8; j++) sacc[i][j] = (f32x4){0.f, 0.f, 0.f, 0.f};
#pragma unroll
            for (int s = 0; s < 2; s++) {
                bf16x8 af[2], bfv[8];
#pragma unroll
                for (int i = 0; i < 2; i++)
                    af[i] = *(const bf16x8*)&qs[(wid * 32 + i * 16 + fr) * 72 + s * 32 + fq * 8];
#pragma unroll
                for (int j = 0; j < 8; j++)
                    bfv[j] = *(const bf16x8*)&upool[(j * 16 + fr) * 72 + s * 32 + fq * 8];
#pragma unroll
                for (int i = 0; i < 2; i++)
#pragma unroll
                    for (int j = 0; j < 8; j++)
                        sacc[i][j] = __builtin_amdgcn_mfma_f32_16x16x32_bf16(af[i], bfv[j], sacc[i][j], 0, 0, 0);
            }
            __syncthreads();

#pragma unroll
            for (int i = 0; i < 2; i++) {
#pragma unroll
                for (int g = 0; g < 4; g++) {
                    float mx = -3.4e38f;
#pragma unroll
                    for (int j = 0; j < 8; j++) mx = fmaxf(mx, sacc[i][j][g]);
                    mx *= 0.125f;
#pragma unroll
                    for (int msk = 1; msk <= 8; msk <<= 1) mx = fmaxf(mx, __shfl_xor(mx, msk, 64));
                    float mnew = fmaxf(mrow[i][g], mx);
                    float alpha = __expf(mrow[i][g] - mnew);
                    mrow[i][g] = mnew;
                    float sum = 0.f;
                    int prow = (wid * 32 + i * 16 + fq * 4 + g) * 136;
#pragma unroll
                    for (int j = 0; j < 8; j++) {
                        float p = __expf(sacc[i][j][g] * 0.125f - mnew);
                        sum += p;
                        upool[prow + j * 16 + fr] = (bf16)p;
                    }
#pragma unroll
                    for (int msk = 1; msk <= 8; msk <<= 1) sum += __shfl_xor(sum, msk, 16);
                    lrow[i][g] = lrow[i][g] * alpha + sum;
#pragma unroll
                    for (int jd = 0; jd < 4; jd++) oaccv[i][jd][g] *= alpha;
                }
            }
            __syncthreads();

#pragma unroll
            for (int s2 = 0; s2 < 4; s2++) {
                bf16x8 pa[2], vb[4];
#pragma unroll
                for (int i = 0; i < 2; i++)
                    pa[i] = *(const bf16x8*)&upool[(wid * 32 + i * 16 + fr) * 136 + s2 * 32 + fq * 8];
#pragma unroll
                for (int jd = 0; jd < 4; jd++)
                    vb[jd] = *(const bf16x8*)&vt[(jd * 16 + fr) * 136 + s2 * 32 + fq * 8];
#pragma unroll
                for (int i = 0; i < 2; i++)
#pragma unroll
                    for (int jd = 0; jd < 4; jd++)
                        oaccv[i][jd] = __builtin_amdgcn_mfma_f32_16x16x32_bf16(pa[i], vb[jd], oaccv[i][jd], 0, 0, 0);
            }
        }

        if (pass == 0) {
#pragma unroll
            for (int i = 0; i < 2; i++)
#pragma unroll
                for (int jd = 0; jd < 4; jd++)
#pragma unroll
                    for (int g = 0; g < 4; g++)
                        o1[i][jd][g] = oaccv[i][jd][g] / lrow[i][g];
        } else {
#pragma unroll
            for (int i = 0; i < 2; i++)
#pragma unroll
                for (int jd = 0; jd < 4; jd++)
#pragma unroll
                    for (int g = 0; g < 4; g++) {
                        float dd = o1[i][jd][g] - oaccv[i][jd][g] / lrow[i][g];
                        local += dd * dd;
                    }
        }
    }

#pragma unroll
    for (int off = 32; off; off >>= 1) local += __shfl_xor(local, off, 64);
    if (lane == 0) wred[wid] = local;
    __syncthreads();
    if (tid == 0)
        partials[(long)by * 4 + bx] = wred[0] + wred[1] + wred[2] + wred[3];
}

// ---------------------------------------------------------------------------
// Launch A: kv (0..1151) | q (1152..1407) | conv split-K (1408..1663)
// ---------------------------------------------------------------------------
__global__ __launch_bounds__(256)
void gemmA_kernel(const bf16* __restrict__ xb, const bf16* __restrict__ memb,
                  const bf16* __restrict__ cmemb,
                  const bf16* __restrict__ WqTb, const bf16* __restrict__ WkvTb,
                  const bf16* __restrict__ convwTb,
                  bf16* __restrict__ qb, bf16* __restrict__ kb, bf16* __restrict__ vTb,
                  float* __restrict__ pbuf)
{
    __shared__ bf16 As[128 * 32];
    __shared__ bf16 Bs[128 * 32];
    int gid = blockIdx.x;
    if (gid < 1152) {
        gemm_body<1, 5>(gid % 16, gid / 16, 0, nullptr, WkvTb, nullptr, kb, vTb,
                        2048, 1024, 1024, 1024, 2048, nullptr, 1152,
                        cmemb, memb, xb, As, Bs);
    } else if (gid < 1408) {
        int g = gid - 1152;
        gemm_body<0, 4>(g % 8, g / 8, 0, xb, WqTb, nullptr, qb, nullptr,
                        1024, 1024, 1024, 1024, 1024, nullptr, 0,
                        nullptr, nullptr, nullptr, As, Bs);
    } else {
        int g = gid - 1408;
        gemm_body<0, 8>(g % 8, (g / 8) % 8, g / 64, memb, convwTb, pbuf, nullptr, nullptr,
                        1024, 1024, 4096, 4096, 1024, nullptr, 0,
                        nullptr, nullptr, nullptr, As, Bs);
    }
}

// ckv standalone: 128 blocks
__global__ __launch_bounds__(256)
void ckv_kernel(const bf16* __restrict__ ncmemb, const bf16* __restrict__ WkvTb,
                bf16* __restrict__ ckb, bf16* __restrict__ cvT)
{
    __shared__ bf16 As[128 * 32];
    __shared__ bf16 Bs[128 * 32];
    gemm_body<0, 5>(blockIdx.x % 16, blockIdx.x / 16, 0, ncmemb, WkvTb, nullptr, ckb, cvT,
                    2048, 1024, 1024, 1024, 2048, nullptr, 128,
                    nullptr, nullptr, nullptr, As, Bs);
}

// ---------------------------------------------------------------------------
// Fused attention (round-10 best + dead pos-tile elision)
// ---------------------------------------------------------------------------
#define SSTR 1164

__global__ __launch_bounds__(256)
void attn_fused16(const bf16* __restrict__ qb, const bf16* __restrict__ kb,
                  const bf16* __restrict__ peb, const bf16* __restrict__ vTb,
                  float* __restrict__ weights, bf16* __restrict__ oatb)
{
    int bid = blockIdx.x;
    int w = (bid & 7) * 512 + (bid >> 3);
    int z = w >> 5;
    int b = z >> 4, h = z & 15;
    int r0 = (w & 31) * 16;
    int tid = threadIdx.x;
    int lane = tid & 63, wid = tid >> 6;
    int fr = lane & 15, fq = lane >> 4;

    __shared__ bf16 S[16 * SSTR];

    bf16x8 afr[2];
#pragma unroll
    for (int ks = 0; ks < 2; ks++)
        afr[ks] = *(const bf16x8*)&qb[((long)(b * 512 + r0 + fr)) * 1024 + h * 64 + ks * 32 + fq * 8];

#pragma unroll 3
    for (int ch = 0; ch < 9; ch++) {
        int c0 = ch * 128;
        int jb0 = c0 + 496 - r0 + 32 * wid;

        f32x4 p[3];
#pragma unroll
        for (int ct = 0; ct < 3; ct++) {
            f32x4 a = (f32x4){0.f, 0.f, 0.f, 0.f};
            int jt0 = jb0 + ct * 16;
            if (jt0 < 1152) {             // wave-uniform: tile has in-range cols
                int j = jt0 + fr;
                bool ok = (j < 1152);
#pragma unroll
                for (int ks = 0; ks < 2; ks++) {
                    bf16x8 bv = {};
                    if (ok) bv = *(const bf16x8*)&peb[((long)(h * 1152 + j)) * 64 + ks * 32 + fq * 8];
                    a = __builtin_amdgcn_mfma_f32_16x16x32_bf16(afr[ks], bv, a, 0, 0, 0);
                }
            }
            p[ct] = a;
        }

#pragma unroll
        for (int tt = 0; tt < 2; tt++) {
            int cc = 32 * wid + 16 * tt + fr;
            f32x4 a = (f32x4){0.f, 0.f, 0.f, 0.f};
            long krow = (long)(b * 1152 + c0 + cc);
#pragma unroll
            for (int ks = 0; ks < 2; ks++) {
                bf16x8 bv = *(const bf16x8*)&kb[krow * 1024 + h * 64 + ks * 32 + fq * 8];
                a = __builtin_amdgcn_mfma_f32_16x16x32_bf16(afr[ks], bv, a, 0, 0, 0);
            }
#pragma unroll
            for (int g = 0; g < 4; g++) {
                int rr = fq * 4 + g;
                int uu = fr + 15 - rr;
                int src = (uu & 15) | (fq << 4);
                float s0 = __shfl(p[tt][g], src, 64);
                float s1 = __shfl(p[tt + 1][g], src, 64);
                float pv = (uu < 16) ? s0 : s1;
                S[rr * SSTR + c0 + cc] = (bf16)(0.125f * (a[g] + pv));
            }
        }
    }
    __syncthreads();

    for (int rw = 0; rw < 4; rw++) {
        int row = wid * 4 + rw;
        bf16* Srow = &S[row * SSTR];
        bf16x8 v0 = *(const bf16x8*)&Srow[lane * 8];
        bf16x8 v1 = *(const bf16x8*)&Srow[512 + lane * 8];
        bf16x2 v2 = *(const bf16x2*)&Srow[1024 + lane * 2];
        float e[18];
#pragma unroll
        for (int j = 0; j < 8; j++) { e[j] = (float)v0[j]; e[8 + j] = (float)v1[j]; }
        e[16] = (float)v2[0]; e[17] = (float)v2[1];

        float m = e[0];
#pragma unroll
        for (int k = 1; k < 18; k++) m = fmaxf(m, e[k]);
#pragma unroll
        for (int off = 32; off; off >>= 1) m = fmaxf(m, __shfl_xor(m, off, 64));
        float sm = 0.f;
#pragma unroll
        for (int k = 0; k < 18; k++) { e[k] = __expf(e[k] - m); sm += e[k]; }
#pragma unroll
        for (int off = 32; off; off >>= 1) sm += __shfl_xor(sm, off, 64);
        float inv = 1.f / sm;

        bf16x8 w0, w1; bf16x2 w2;
#pragma unroll
        for (int j = 0; j < 8; j++) { w0[j] = (bf16)(e[j] * inv); w1[j] = (bf16)(e[8 + j] * inv); }
        w2[0] = (bf16)(e[16] * inv); w2[1] = (bf16)(e[17] * inv);
        *(bf16x8*)&Srow[lane * 8] = w0;
        *(bf16x8*)&Srow[512 + lane * 8] = w1;
        *(bf16x2*)&Srow[1024 + lane * 2] = w2;
    }
    __syncthreads();

    f32x4 oacc = (f32x4){0.f, 0.f, 0.f, 0.f};
    int dt = wid;
    for (int ch = 0; ch < 9; ch++) {
        int c0 = ch * 128;
#pragma unroll
        for (int ks = 0; ks < 4; ks++) {
            bf16x8 pa = *(const bf16x8*)&S[fr * SSTR + c0 + ks * 32 + fq * 8];
            bf16x8 vb = *(const bf16x8*)&vTb[((long)z * 64 + dt * 16 + fr) * 1152 + c0 + ks * 32 + fq * 8];
            oacc = __builtin_amdgcn_mfma_f32_16x16x32_bf16(pa, vb, oacc, 0, 0, 0);
        }
    }
#pragma unroll
    for (int g = 0; g < 4; g++)
        oatb[((long)(b * 512 + r0 + fq * 4 + g)) * 1024 + h * 64 + dt * 16 + fr] = (bf16)oacc[g];

    for (int rw = 0; rw < 4; rw++) {
        int row = wid * 4 + rw;
        const bf16* Srow = &S[row * SSTR];
        long wbase = ((long)z * 512 + r0 + row) * 1152;
        bf16x8 v0 = *(const bf16x8*)&Srow[lane * 8];
        bf16x8 v1 = *(const bf16x8*)&Srow[512 + lane * 8];
        bf16x2 v2 = *(const bf16x2*)&Srow[1024 + lane * 2];
        f32x4 a0 = { (float)v0[0], (float)v0[1], (float)v0[2], (float)v0[3] };
        f32x4 a1 = { (float)v0[4], (float)v0[5], (float)v0[6], (float)v0[7] };
        f32x4 b0 = { (float)v1[0], (float)v1[1], (float)v1[2], (float)v1[3] };
        f32x4 b1 = { (float)v1[4], (float)v1[5], (float)v1[6], (float)v1[7] };
        f32x2 c0 = { (float)v2[0], (float)v2[1] };
        __builtin_nontemporal_store(a0, (f32x4*)&weights[wbase + lane * 8]);
        __builtin_nontemporal_store(a1, (f32x4*)&weights[wbase + lane * 8 + 4]);
        __builtin_nontemporal_store(b0, (f32x4*)&weights[wbase + 512 + lane * 8]);
        __builtin_nontemporal_store(b1, (f32x4*)&weights[wbase + 512 + lane * 8 + 4]);
        __builtin_nontemporal_store(c0, (f32x2*)&weights[wbase + 1024 + lane * 2]);
    }
}

// Launch C: aux (0..511) | logits (512..767)
__global__ __launch_bounds__(256)
void logits_aux_kernel(const bf16* __restrict__ qb, const bf16* __restrict__ kb,
                       const bf16* __restrict__ ckb,
                       const bf16* __restrict__ vTb, const bf16* __restrict__ cvT,
                       float* __restrict__ partials,
                       const bf16* __restrict__ oatb, const bf16* __restrict__ WoutTb,
                       float* __restrict__ out_logits, const float* __restrict__ bout)
{
    __shared__ bf16 pool[35328];   // qs 9216 | upool 17408 | vt 8704
    __shared__ float wred[4];
    int gid = blockIdx.x;
    if (gid < 512) {
        aux_body(gid % 4, gid / 4, qb, kb, ckb, vTb, cvT, partials,
                 pool, pool + 9216, pool + 26624, wred);
    } else {
        int g = gid - 512;
        gemm_body<0, 6>(g % 8, g / 8, 0, oatb, WoutTb, out_logits, nullptr, nullptr,
                        1024, 1024, 1024, 1024, 1024, bout, 0,
                        nullptr, nullptr, nullptr, pool, pool + 4096);
    }
}

// split-K reduce
__global__ __launch_bounds__(256)
void splitk_reduce(const float* __restrict__ pbuf, const float* __restrict__ bias,
                   float* __restrict__ outF, bf16* __restrict__ outB)
{
    int i = blockIdx.x * 256 + threadIdx.x;
    f32x4 s = reinterpret_cast<const f32x4*>(pbuf)[i];
#pragma unroll
    for (int k = 1; k < 4; k++) {
        f32x4 t = reinterpret_cast<const f32x4*>(pbuf + (long)k * 1048576)[i];
        s[0] += t[0]; s[1] += t[1]; s[2] += t[2]; s[3] += t[3];
    }
    int col4 = (i << 2) & 1023;
    f32x4 bv = *(const f32x4*)&bias[col4];
    s[0] += bv[0]; s[1] += bv[1]; s[2] += bv[2]; s[3] += bv[3];
    reinterpret_cast<f32x4*>(outF)[i] = s;
    bf16x4 h = { (bf16)s[0], (bf16)s[1], (bf16)s[2], (bf16)s[3] };
    reinterpret_cast<bf16x4*>(outB)[i] = h;
}

// ---------------------------------------------------------------------------
// Prologue bodies
// ---------------------------------------------------------------------------
__device__ __forceinline__ void transpose_body(
    int bx, int by, const float* __restrict__ in, bf16* __restrict__ out,
    int R, int C, float* t /* 32*33 floats */)
{
    int c0 = bx * 32, r0 = by * 32;
    int tx = threadIdx.x & 31, ty = threadIdx.x >> 5;
#pragma unroll
    for (int i = 0; i < 32; i += 8)
        t[(ty + i) * 33 + tx] = in[(long)(r0 + ty + i) * C + c0 + tx];
    __syncthreads();
#pragma unroll
    for (int i = 0; i < 32; i += 8)
        out[(long)(c0 + ty + i) * R + r0 + tx] = (bf16)t[tx * 33 + ty + i];
}

__device__ __forceinline__ void convw_body(
    int o, const float* __restrict__ cw, bf16* __restrict__ out, float* t /*4096*/)
{
    const float* src = cw + (long)o * 4096;
    bf16* dst = out + (long)o * 4096;
#pragma unroll
    for (int k = 0; k < 4; k++)
        *(f32x4*)&t[(threadIdx.x + k * 256) * 4] = *(const f32x4*)&src[(threadIdx.x + k * 256) * 4];
    __syncthreads();
#pragma unroll
    for (int k = 0; k < 8; k++) {
        int d2 = 2 * (threadIdx.x + k * 256);
        int pi = ((d2 & 1023) << 2) | (d2 >> 10);
        bf16x2 h = { (bf16)t[pi], (bf16)t[pi + 4] };
        *(bf16x2*)&dst[d2] = h;
    }
}

// prologue: Wq T | Wkv T | Wout T | convw | casts
__global__ __launch_bounds__(256)
void prologue_kernel(const float* __restrict__ Wq, bf16* __restrict__ WqTb,
                     const float* __restrict__ Wkv, bf16* __restrict__ WkvTb,
                     const float* __restrict__ Wout, bf16* __restrict__ WoutTb,
                     const float* __restrict__ conv_w, bf16* __restrict__ convwTb,
                     const float* __restrict__ pe, bf16* __restrict__ peb,
                     const float* __restrict__ x, bf16* __restrict__ xb,
                     const float* __restrict__ mem, bf16* __restrict__ memb,
                     const float* __restrict__ cmem, bf16* __restrict__ cmemb,
                     float* __restrict__ xmirror)
{
    __shared__ float t[4096];
    int gid = blockIdx.x;
    if (gid < 1024) {
        transpose_body(gid & 31, gid >> 5, Wq, WqTb, 1024, 1024, t);
    } else if (gid < 3072) {
        int g = gid - 1024;
        transpose_body(g & 63, g >> 6, Wkv, WkvTb, 1024, 2048, t);
    } else if (gid < 4096) {
        int g = gid - 3072;
        transpose_body(g & 31, g >> 5, Wout, WoutTb, 1024, 1024, t);
    } else if (gid < 5120) {
        convw_body(gid - 4096, conv_w, convwTb, t);
    } else {
        int i0 = (gid - 5120) * 256 + threadIdx.x;
        const int n0 = 294912, n1 = 1048576, n2 = 1048576, n3 = 262144;
        for (int i = i0; i < n0 + n1 + n2 + n3; i += 2048 * 256) {
            const float* src; bf16* dst; int k = i; int seg;
            if (k < n0) { src = pe; dst = peb; seg = 0; }
            else if ((k -= n0) < n1) { src = x; dst = xb; seg = 1; }
            else if ((k -= n1) < n2) { src = mem; dst = memb; seg = 2; }
            else { k -= n2; src = cmem; dst = cmemb; seg = 3; }
            f32x4 f = reinterpret_cast<const f32x4*>(src)[k];
            bf16x4 h = { (bf16)f[0], (bf16)f[1], (bf16)f[2], (bf16)f[3] };
            reinterpret_cast<bf16x4*>(dst)[k] = h;
            if (seg == 1)
                __builtin_nontemporal_store(f, &reinterpret_cast<f32x4*>(xmirror)[k]);
        }
    }
}

__global__ __launch_bounds__(256)
void aux_reduce_kernel(const float* __restrict__ partials, float* __restrict__ out)
{
    int tid = threadIdx.x;
    __shared__ float wred[4];
    float s = 0.f;
    for (int i = tid; i < 512; i += 256) s += partials[i];
#pragma unroll
    for (int off = 32; off; off >>= 1) s += __shfl_xor(s, off, 64);
    if ((tid & 63) == 0) wred[tid >> 6] = s;
    __syncthreads();
    if (tid == 0) out[0] = (wred[0] + wred[1] + wred[2] + wred[3]) * (1.0f / 4194304.0f);
}

extern "C" void kernel_launch(void* const* d_in, const int* in_sizes, int n_in,
                              void* d_out, int out_size, void* d_ws, size_t ws_size,
                              hipStream_t stream)
{
    const float* x      = (const float*)d_in[0];
    const float* mem    = (const float*)d_in[1];
    const float* cmem   = (const float*)d_in[2];
    const float* pe     = (const float*)d_in[3];
    const float* Wq     = (const float*)d_in[4];
    const float* Wkv    = (const float*)d_in[5];
    const float* Wout   = (const float*)d_in[6];
    const float* bout   = (const float*)d_in[7];
    const float* conv_w = (const float*)d_in[8];
    const float* conv_b = (const float*)d_in[9];

    float* out_logits  = (float*)d_out;                 // 8*512*1024
    float* out_newmem  = out_logits + 4194304;          // 8*512*1024
    float* out_newcmem = out_newmem + 4194304;          // 8*128*1024
    float* out_aux     = out_newcmem + 1048576;         // 1
    float* out_weights = out_aux + 1;                   // 8*16*512*1152

    float* ws       = (float*)d_ws;
    float* partials = ws;                    // 4096 f
    float* pbuf     = partials + 4096;       // 4 * 1,048,576 f
    bf16* bws     = (bf16*)(pbuf + 4194304);
    bf16* WqTb    = bws;                     // 1,048,576
    bf16* WkvTb   = WqTb + 1048576;          // 2,097,152
    bf16* WoutTb  = WkvTb + 2097152;         // 1,048,576
    bf16* convwTb = WoutTb + 1048576;        // 4,194,304
    bf16* vTb     = convwTb + 4194304;       // 9,437,184
    bf16* cvT     = vTb + 9437184;           // 1,048,576
    bf16* qb      = cvT + 1048576;           // 4,194,304
    bf16* kb      = qb + 4194304;            // 9,437,184
    bf16* ckb     = kb + 9437184;            // 1,048,576
    bf16* peb     = ckb + 1048576;           // 1,179,648
    bf16* xb      = peb + 1179648;           // 4,194,304
    bf16* memb    = xb + 4194304;            // 4,194,304
    bf16* cmemb   = memb + 4194304;          // 1,048,576
    bf16* ncmemb  = cmemb + 1048576;         // 1,048,576
    bf16* oatb    = ncmemb + 1048576;        // 4,194,304

    dim3 blk(256);

    // merged prologue: weight transposes + convw cast + input casts
    prologue_kernel<<<dim3(7168), blk, 0, stream>>>(
        Wq, WqTb, Wkv, WkvTb, Wout, WoutTb, conv_w, convwTb,
        pe, peb, x, xb, mem, memb, cmem, cmemb, out_newmem);

    // Launch A: kv + q + conv split-K
    gemmA_kernel<<<dim3(1664), blk, 0, stream>>>(
        xb, memb, cmemb, WqTb, WkvTb, convwTb, qb, kb, vTb, pbuf);

    // reduce partials + bias -> new_cmem (fp32) + ncmemb (bf16)
    splitk_reduce<<<dim3(1024), blk, 0, stream>>>(pbuf, conv_b, out_newcmem, ncmemb);

    // ckv standalone (128 blocks)
    ckv_kernel<<<dim3(128), blk, 0, stream>>>(ncmemb, WkvTb, ckb, cvT);

    // fused attention (standalone, 52 VGPR)
    attn_fused16<<<dim3(4096), blk, 0, stream>>>(qb, kb, peb, vTb, out_weights, oatb);

    // Launch C: aux + logits
    logits_aux_kernel<<<dim3(768), blk, 0, stream>>>(
        qb, kb, ckb, vTb, cvT, partials, oatb, WoutTb, out_logits, bout);

    aux_reduce_kernel<<<dim3(1), blk, 0, stream>>>(partials, out_aux);
}

// Round 27
// 486.965 us; speedup vs baseline: 1.0084x; 1.0007x over previous
//
#include <hip/hip_runtime.h>
#include <cstdint>

// HEADS=16, DIM=1024, SEQ=512, MEM=512, CMEM=128, RATIO=4, DIM_H=64, b=8, kv_len=1152

typedef __bf16 bf16;
typedef __bf16 bf16x2 __attribute__((ext_vector_type(2)));
typedef __bf16 bf16x4 __attribute__((ext_vector_type(4)));
typedef __bf16 bf16x8 __attribute__((ext_vector_type(8)));
typedef float  f32x2  __attribute__((ext_vector_type(2)));
typedef float  f32x4  __attribute__((ext_vector_type(4)));

#define GLOAD_LDS16(g, l) \
    __builtin_amdgcn_global_load_lds((const __attribute__((address_space(1))) void*)(g), \
                                     (__attribute__((address_space(3))) void*)(l), 16, 0, 0)

// ---------------------------------------------------------------------------
// GEMM body: tile 128x128, BK=32, 4 waves, global_load_lds staging, XOR swizzle.
// ---------------------------------------------------------------------------
template<int AMODE, int EPI>
__device__ __forceinline__ void gemm_body(
    int bx, int by, int bz,
    const bf16* __restrict__ A, const bf16* __restrict__ B2,
    float* __restrict__ C, bf16* __restrict__ outB, bf16* __restrict__ vT,
    int N, int K, int lda, int ldbt, int ldc,
    const float* __restrict__ bias, int vrows,
    const bf16* __restrict__ gcmem, const bf16* __restrict__ gmem,
    const bf16* __restrict__ gx,
    bf16* As, bf16* Bs)
{
    int row0 = by * 128, col0 = bx * 128;
    int tid = threadIdx.x;
    int kofs = (EPI == 8) ? bz * K : 0;

    int lane = tid & 63, wid = tid >> 6;
    int wr = wid >> 1, wc = wid & 1;
    int fr = lane & 15, fq = lane >> 4;

    int srow = lane >> 2;
    int sc16 = (lane & 3) ^ ((lane >> 3) & 3);
    const bf16* aq[2];
    const bf16* bq[2];
    bf16* as_dst[2];
    bf16* bs_dst[2];
#pragma unroll
    for (int t = 0; t < 2; t++) {
        int gr = row0 + wid * 32 + t * 16 + srow;
        const bf16* ap;
        if (AMODE == 0) {
            ap = A + (long)gr * lda + kofs;
        } else {
            int bb = gr / 1152, rr = gr - bb * 1152;
            ap = (rr < 128) ? (gcmem + ((long)bb * 128 + rr) * 1024)
               : (rr < 640) ? (gmem + ((long)bb * 512 + (rr - 128)) * 1024)
                            : (gx   + ((long)bb * 512 + (rr - 640)) * 1024);
        }
        aq[t] = ap + sc16 * 8;
        int gc = col0 + wid * 32 + t * 16 + srow;
        bq[t] = B2 + (long)gc * ldbt + kofs + sc16 * 8;
        as_dst[t] = &As[(wid * 32 + t * 16) * 32];
        bs_dst[t] = &Bs[(wid * 32 + t * 16) * 32];
    }

    int sfq = (fq ^ ((fr >> 1) & 3)) * 8;

    f32x4 acc[4][4];
#pragma unroll
    for (int i = 0; i < 4; i++)
#pragma unroll
        for (int j = 0; j < 4; j++) acc[i][j] = (f32x4){0.f, 0.f, 0.f, 0.f};

    for (int k0 = 0; k0 < K; k0 += 32) {
#pragma unroll
        for (int t = 0; t < 2; t++) {
            GLOAD_LDS16(aq[t] + k0, as_dst[t]);
            GLOAD_LDS16(bq[t] + k0, bs_dst[t]);
        }
        __syncthreads();

        bf16x8 af[4], bfv[4];
#pragma unroll
        for (int i = 0; i < 4; i++)
            af[i] = *(const bf16x8*)&As[(wr * 64 + i * 16 + fr) * 32 + sfq];
#pragma unroll
        for (int j = 0; j < 4; j++)
            bfv[j] = *(const bf16x8*)&Bs[(wc * 64 + j * 16 + fr) * 32 + sfq];
#pragma unroll
        for (int i = 0; i < 4; i++)
#pragma unroll
            for (int j = 0; j < 4; j++)
                acc[i][j] = __builtin_amdgcn_mfma_f32_16x16x32_bf16(af[i], bfv[j], acc[i][j], 0, 0, 0);
        __syncthreads();
    }

#pragma unroll
    for (int i = 0; i < 4; i++) {
#pragma unroll
        for (int j = 0; j < 4; j++) {
#pragma unroll
            for (int g = 0; g < 4; g++) {
                int r = row0 + wr * 64 + i * 16 + fq * 4 + g;
                int c = col0 + wc * 64 + j * 16 + fr;
                float v = acc[i][j][g];
                if (EPI == 0) {
                    if (bias) v += bias[c];
                    C[(long)r * ldc + c] = v;
                } else if (EPI == 6) {
                    if (bias) v += bias[c];
                    __builtin_nontemporal_store(v, &C[(long)r * ldc + c]);
                } else if (EPI == 8) {
                    C[((long)bz << 20) + (long)r * 1024 + c] = v;
                } else if (EPI == 4) {
                    outB[(long)r * ldc + c] = (bf16)v;
                } else { // EPI == 5
                    if (c < 1024) {
                        outB[(long)r * 1024 + c] = (bf16)v;
                    } else {
                        int d = c - 1024; int hh = d >> 6; d &= 63;
                        int bb = r / vrows; int j2 = r - bb * vrows;
                        vT[(((long)(bb * 16 + hh)) * 64 + d) * vrows + j2] = (bf16)v;
                    }
                }
            }
        }
    }
}

// ---------------------------------------------------------------------------
// aux body (round-10 structure), shared carved from pool.
// ---------------------------------------------------------------------------
__device__ __forceinline__ void aux_body(
    int bx, int by,
    const bf16* __restrict__ qb, const bf16* __restrict__ kb,
    const bf16* __restrict__ ckb,
    const bf16* __restrict__ vTb, const bf16* __restrict__ cvT,
    float* __restrict__ partials,
    bf16* qs, bf16* upool, bf16* vt, float* wred)
{
    int z = by;
    int b = z >> 4, h = z & 15;
    int r0 = bx * 128;
    int tid = threadIdx.x;
    int lane = tid & 63, wid = tid >> 6;
    int fr = lane & 15, fq = lane >> 4;

#pragma unroll
    for (int t = 0; t < 4; t++) {
        int e = tid + 256 * t; int rr = e >> 3, c8 = (e & 7) * 8;
        *(bf16x8*)&qs[rr * 72 + c8] = *(const bf16x8*)&qb[((long)(b * 512 + r0 + rr)) * 1024 + h * 64 + c8];
    }

    float o1[2][4][4];
    f32x4 oaccv[2][4];
    float mrow[2][4], lrow[2][4];
    f32x4 sacc[2][8];
    float local = 0.f;

    for (int pass = 0; pass < 2; pass++) {
#pragma unroll
        for (int i = 0; i < 2; i++)
#pragma unroll
            for (int g = 0; g < 4; g++) { mrow[i][g] = -3.4e38f; lrow[i][g] = 0.f; }
#pragma unroll
        for (int i = 0; i < 2; i++)
#pragma unroll
            for (int jd = 0; jd < 4; jd++) oaccv[i][jd] = (f32x4){0.f, 0.f, 0.f, 0.f};

        int nchunk = pass ? 1 : 4;
        for (int jt = 0; jt < nchunk; jt++) {
            __syncthreads();
            if (pass == 0) {
                long base = (long)(b * 1152 + 128 + jt * 128);
#pragma unroll
                for (int t = 0; t < 4; t++) {
                    int e = tid + 256 * t; int j = e >> 3, c8 = (e & 7) * 8;
                    *(bf16x8*)&upool[j * 72 + c8] = *(const bf16x8*)&kb[(base + j) * 1024 + h * 64 + c8];
                }
#pragma unroll
                for (int t = 0; t < 4; t++) {
                    int e = tid + 256 * t; int d = e >> 4, j8 = (e & 15) * 8;
                    *(bf16x8*)&vt[d * 136 + j8] =
                        *(const bf16x8*)&vTb[((long)z * 64 + d) * 1152 + 128 + jt * 128 + j8];
                }
            } else {
#pragma unroll
                for (int t = 0; t < 4; t++) {
                    int e = tid + 256 * t; int j = e >> 3, c8 = (e & 7) * 8;
                    *(bf16x8*)&upool[j * 72 + c8] = *(const bf16x8*)&ckb[((long)(b * 128 + j)) * 1024 + h * 64 + c8];
                }
#pragma unroll
                for (int t = 0; t < 4; t++) {
                    int e = tid + 256 * t; int d = e >> 4, j8 = (e & 15) * 8;
                    *(bf16x8*)&vt[d * 136 + j8] = *(const bf16x8*)&cvT[((long)z * 64 + d) * 128 + j8];
                }
            }
            __syncthreads();

#pragma unroll
            for (int i = 0; i < 2; i++)
#pragma unroll
                for (int j = 0; j < 8; j++) sacc[i][j] = (f32x4){0.f, 0.f, 0.f, 0.f};
#pragma unroll
            for (int s = 0; s < 2; s++) {
                bf16x8 af[2], bfv[8];
#pragma unroll
                for (int i = 0; i < 2; i++)
                    af[i] = *(const bf16x8*)&qs[(wid * 32 + i * 16 + fr) * 72 + s * 32 + fq * 8];
#pragma unroll
                for (int j = 0; j < 8; j++)
                    bfv[j] = *(const bf16x8*)&upool[(j * 16 + fr) * 72 + s * 32 + fq * 8];
#pragma unroll
                for (int i = 0; i < 2; i++)
#pragma unroll
                    for (int j = 0; j < 8; j++)
                        sacc[i][j] = __builtin_amdgcn_mfma_f32_16x16x32_bf16(af[i], bfv[j], sacc[i][j], 0, 0, 0);
            }
            __syncthreads();

#pragma unroll
            for (int i = 0; i < 2; i++) {
#pragma unroll
                for (int g = 0; g < 4; g++) {
                    float mx = -3.4e38f;
#pragma unroll
                    for (int j = 0; j < 8; j++) mx = fmaxf(mx, sacc[i][j][g]);
                    mx *= 0.125f;
#pragma unroll
                    for (int msk = 1; msk <= 8; msk <<= 1) mx = fmaxf(mx, __shfl_xor(mx, msk, 64));
                    float mnew = fmaxf(mrow[i][g], mx);
                    float alpha = __expf(mrow[i][g] - mnew);
                    mrow[i][g] = mnew;
                    float sum = 0.f;
                    int prow = (wid * 32 + i * 16 + fq * 4 + g) * 136;
#pragma unroll
                    for (int j = 0; j < 8; j++) {
                        float p = __expf(sacc[i][j][g] * 0.125f - mnew);
                        sum += p;
                        upool[prow + j * 16 + fr] = (bf16)p;
                    }
#pragma unroll
                    for (int msk = 1; msk <= 8; msk <<= 1) sum += __shfl_xor(sum, msk, 16);
                    lrow[i][g] = lrow[i][g] * alpha + sum;
#pragma unroll
                    for (int jd = 0; jd < 4; jd++) oaccv[i][jd][g] *= alpha;
                }
            }
            __syncthreads();

#pragma unroll
            for (int s2 = 0; s2 < 4; s2++) {
                bf16x8 pa[2], vb[4];
#pragma unroll
                for (int i = 0; i < 2; i++)
                    pa[i] = *(const bf16x8*)&upool[(wid * 32 + i * 16 + fr) * 136 + s2 * 32 + fq * 8];
#pragma unroll
                for (int jd = 0; jd < 4; jd++)
                    vb[jd] = *(const bf16x8*)&vt[(jd * 16 + fr) * 136 + s2 * 32 + fq * 8];
#pragma unroll
                for (int i = 0; i < 2; i++)
#pragma unroll
                    for (int jd = 0; jd < 4; jd++)
                        oaccv[i][jd] = __builtin_amdgcn_mfma_f32_16x16x32_bf16(pa[i], vb[jd], oaccv[i][jd], 0, 0, 0);
            }
        }

        if (pass == 0) {
#pragma unroll
            for (int i = 0; i < 2; i++)
#pragma unroll
                for (int jd = 0; jd < 4; jd++)
#pragma unroll
                    for (int g = 0; g < 4; g++)
                        o1[i][jd][g] = oaccv[i][jd][g] / lrow[i][g];
        } else {
#pragma unroll
            for (int i = 0; i < 2; i++)
#pragma unroll
                for (int jd = 0; jd < 4; jd++)
#pragma unroll
                    for (int g = 0; g < 4; g++) {
                        float dd = o1[i][jd][g] - oaccv[i][jd][g] / lrow[i][g];
                        local += dd * dd;
                    }
        }
    }

#pragma unroll
    for (int off = 32; off; off >>= 1) local += __shfl_xor(local, off, 64);
    if (lane == 0) wred[wid] = local;
    __syncthreads();
    if (tid == 0)
        partials[(long)by * 4 + bx] = wred[0] + wred[1] + wred[2] + wred[3];
}

// ---------------------------------------------------------------------------
// Launch A: kv (0..1151) | q (1152..1407) | conv split-K (1408..1663)
// ---------------------------------------------------------------------------
__global__ __launch_bounds__(256)
void gemmA_kernel(const bf16* __restrict__ xb, const bf16* __restrict__ memb,
                  const bf16* __restrict__ cmemb,
                  const bf16* __restrict__ WqTb, const bf16* __restrict__ WkvTb,
                  const bf16* __restrict__ convwTb,
                  bf16* __restrict__ qb, bf16* __restrict__ kb, bf16* __restrict__ vTb,
                  float* __restrict__ pbuf)
{
    __shared__ bf16 As[128 * 32];
    __shared__ bf16 Bs[128 * 32];
    int gid = blockIdx.x;
    if (gid < 1152) {
        gemm_body<1, 5>(gid % 16, gid / 16, 0, nullptr, WkvTb, nullptr, kb, vTb,
                        2048, 1024, 1024, 1024, 2048, nullptr, 1152,
                        cmemb, memb, xb, As, Bs);
    } else if (gid < 1408) {
        int g = gid - 1152;
        gemm_body<0, 4>(g % 8, g / 8, 0, xb, WqTb, nullptr, qb, nullptr,
                        1024, 1024, 1024, 1024, 1024, nullptr, 0,
                        nullptr, nullptr, nullptr, As, Bs);
    } else {
        int g = gid - 1408;
        gemm_body<0, 8>(g % 8, (g / 8) % 8, g / 64, memb, convwTb, pbuf, nullptr, nullptr,
                        1024, 1024, 4096, 4096, 1024, nullptr, 0,
                        nullptr, nullptr, nullptr, As, Bs);
    }
}

// ckv standalone: 128 blocks
__global__ __launch_bounds__(256)
void ckv_kernel(const bf16* __restrict__ ncmemb, const bf16* __restrict__ WkvTb,
                bf16* __restrict__ ckb, bf16* __restrict__ cvT)
{
    __shared__ bf16 As[128 * 32];
    __shared__ bf16 Bs[128 * 32];
    gemm_body<0, 5>(blockIdx.x % 16, blockIdx.x / 16, 0, ncmemb, WkvTb, nullptr, ckb, cvT,
                    2048, 1024, 1024, 1024, 2048, nullptr, 128,
                    nullptr, nullptr, nullptr, As, Bs);
}

// ---------------------------------------------------------------------------
// Fused attention (round-10 best + dead pos-tile elision)
// ---------------------------------------------------------------------------
#define SSTR 1164

__global__ __launch_bounds__(256)
void attn_fused16(const bf16* __restrict__ qb, const bf16* __restrict__ kb,
                  const bf16* __restrict__ peb, const bf16* __restrict__ vTb,
                  float* __restrict__ weights, bf16* __restrict__ oatb)
{
    int bid = blockIdx.x;
    int w = (bid & 7) * 512 + (bid >> 3);
    int z = w >> 5;
    int b = z >> 4, h = z & 15;
    int r0 = (w & 31) * 16;
    int tid = threadIdx.x;
    int lane = tid & 63, wid = tid >> 6;
    int fr = lane & 15, fq = lane >> 4;

    __shared__ bf16 S[16 * SSTR];

    bf16x8 afr[2];
#pragma unroll
    for (int ks = 0; ks < 2; ks++)
        afr[ks] = *(const bf16x8*)&qb[((long)(b * 512 + r0 + fr)) * 1024 + h * 64 + ks * 32 + fq * 8];

#pragma unroll 3
    for (int ch = 0; ch < 9; ch++) {
        int c0 = ch * 128;
        int jb0 = c0 + 496 - r0 + 32 * wid;

        f32x4 p[3];
#pragma unroll
        for (int ct = 0; ct < 3; ct++) {
            f32x4 a = (f32x4){0.f, 0.f, 0.f, 0.f};
            int jt0 = jb0 + ct * 16;
            if (jt0 < 1152) {             // wave-uniform: tile has in-range cols
                int j = jt0 + fr;
                bool ok = (j < 1152);
#pragma unroll
                for (int ks = 0; ks < 2; ks++) {
                    bf16x8 bv = {};
                    if (ok) bv = *(const bf16x8*)&peb[((long)(h * 1152 + j)) * 64 + ks * 32 + fq * 8];
                    a = __builtin_amdgcn_mfma_f32_16x16x32_bf16(afr[ks], bv, a, 0, 0, 0);
                }
            }
            p[ct] = a;
        }

#pragma unroll
        for (int tt = 0; tt < 2; tt++) {
            int cc = 32 * wid + 16 * tt + fr;
            f32x4 a = (f32x4){0.f, 0.f, 0.f, 0.f};
            long krow = (long)(b * 1152 + c0 + cc);
#pragma unroll
            for (int ks = 0; ks < 2; ks++) {
                bf16x8 bv = *(const bf16x8*)&kb[krow * 1024 + h * 64 + ks * 32 + fq * 8];
                a = __builtin_amdgcn_mfma_f32_16x16x32_bf16(afr[ks], bv, a, 0, 0, 0);
            }
#pragma unroll
            for (int g = 0; g < 4; g++) {
                int rr = fq * 4 + g;
                int uu = fr + 15 - rr;
                int src = (uu & 15) | (fq << 4);
                float s0 = __shfl(p[tt][g], src, 64);
                float s1 = __shfl(p[tt + 1][g], src, 64);
                float pv = (uu < 16) ? s0 : s1;
                S[rr * SSTR + c0 + cc] = (bf16)(0.125f * (a[g] + pv));
            }
        }
    }
    __syncthreads();

    for (int rw = 0; rw < 4; rw++) {
        int row = wid * 4 + rw;
        bf16* Srow = &S[row * SSTR];
        bf16x8 v0 = *(const bf16x8*)&Srow[lane * 8];
        bf16x8 v1 = *(const bf16x8*)&Srow[512 + lane * 8];
        bf16x2 v2 = *(const bf16x2*)&Srow[1024 + lane * 2];
        float e[18];
#pragma unroll
        for (int j = 0; j < 8; j++) { e[j] = (float)v0[j]; e[8 + j] = (float)v1[j]; }
        e[16] = (float)v2[0]; e[17] = (float)v2[1];

        float m = e[0];
#pragma unroll
        for (int k = 1; k < 18; k++) m = fmaxf(m, e[k]);
#pragma unroll
        for (int off = 32; off; off >>= 1) m = fmaxf(m, __shfl_xor(m, off, 64));
        float sm = 0.f;
#pragma unroll
        for (int k = 0; k < 18; k++) { e[k] = __expf(e[k] - m); sm += e[k]; }
#pragma unroll
        for (int off = 32; off; off >>= 1) sm += __shfl_xor(sm, off, 64);
        float inv = 1.f / sm;

        bf16x8 w0, w1; bf16x2 w2;
#pragma unroll
        for (int j = 0; j < 8; j++) { w0[j] = (bf16)(e[j] * inv); w1[j] = (bf16)(e[8 + j] * inv); }
        w2[0] = (bf16)(e[16] * inv); w2[1] = (bf16)(e[17] * inv);
        *(bf16x8*)&Srow[lane * 8] = w0;
        *(bf16x8*)&Srow[512 + lane * 8] = w1;
        *(bf16x2*)&Srow[1024 + lane * 2] = w2;
    }
    __syncthreads();

    f32x4 oacc = (f32x4){0.f, 0.f, 0.f, 0.f};
    int dt = wid;
    for (int ch = 0; ch < 9; ch++) {
        int c0 = ch * 128;
#pragma unroll
        for (int ks = 0; ks < 4; ks++) {
            bf16x8 pa = *(const bf16x8*)&S[fr * SSTR + c0 + ks * 32 + fq * 8];
            bf16x8 vb = *(const bf16x8*)&vTb[((long)z * 64 + dt * 16 + fr) * 1152 + c0 + ks * 32 + fq * 8];
            oacc = __builtin_amdgcn_mfma_f32_16x16x32_bf16(pa, vb, oacc, 0, 0, 0);
        }
    }
#pragma unroll
    for (int g = 0; g < 4; g++)
        oatb[((long)(b * 512 + r0 + fq * 4 + g)) * 1024 + h * 64 + dt * 16 + fr] = (bf16)oacc[g];

    for (int rw = 0; rw < 4; rw++) {
        int row = wid * 4 + rw;
        const bf16* Srow = &S[row * SSTR];
        long wbase = ((long)z * 512 + r0 + row) * 1152;
        bf16x8 v0 = *(const bf16x8*)&Srow[lane * 8];
        bf16x8 v1 = *(const bf16x8*)&Srow[512 + lane * 8];
        bf16x2 v2 = *(const bf16x2*)&Srow[1024 + lane * 2];
        f32x4 a0 = { (float)v0[0], (float)v0[1], (float)v0[2], (float)v0[3] };
        f32x4 a1 = { (float)v0[4], (float)v0[5], (float)v0[6], (float)v0[7] };
        f32x4 b0 = { (float)v1[0], (float)v1[1], (float)v1[2], (float)v1[3] };
        f32x4 b1 = { (float)v1[4], (float)v1[5], (float)v1[6], (float)v1[7] };
        f32x2 c0 = { (float)v2[0], (float)v2[1] };
        __builtin_nontemporal_store(a0, (f32x4*)&weights[wbase + lane * 8]);
        __builtin_nontemporal_store(a1, (f32x4*)&weights[wbase + lane * 8 + 4]);
        __builtin_nontemporal_store(b0, (f32x4*)&weights[wbase + 512 + lane * 8]);
        __builtin_nontemporal_store(b1, (f32x4*)&weights[wbase + 512 + lane * 8 + 4]);
        __builtin_nontemporal_store(c0, (f32x2*)&weights[wbase + 1024 + lane * 2]);
    }
}

// Launch C: aux (0..511) | logits (512..767)
__global__ __launch_bounds__(256)
void logits_aux_kernel(const bf16* __restrict__ qb, const bf16* __restrict__ kb,
                       const bf16* __restrict__ ckb,
                       const bf16* __restrict__ vTb, const bf16* __restrict__ cvT,
                       float* __restrict__ partials,
                       const bf16* __restrict__ oatb, const bf16* __restrict__ WoutTb,
                       float* __restrict__ out_logits, const float* __restrict__ bout)
{
    __shared__ bf16 pool[35328];   // qs 9216 | upool 17408 | vt 8704
    __shared__ float wred[4];
    int gid = blockIdx.x;
    if (gid < 512) {
        aux_body(gid % 4, gid / 4, qb, kb, ckb, vTb, cvT, partials,
                 pool, pool + 9216, pool + 26624, wred);
    } else {
        int g = gid - 512;
        gemm_body<0, 6>(g % 8, g / 8, 0, oatb, WoutTb, out_logits, nullptr, nullptr,
                        1024, 1024, 1024, 1024, 1024, bout, 0,
                        nullptr, nullptr, nullptr, pool, pool + 4096);
    }
}

// split-K reduce
__global__ __launch_bounds__(256)
void splitk_reduce(const float* __restrict__ pbuf, const float* __restrict__ bias,
                   float* __restrict__ outF, bf16* __restrict__ outB)
{
    int i = blockIdx.x * 256 + threadIdx.x;
    f32x4 s = reinterpret_cast<const f32x4*>(pbuf)[i];
#pragma unroll
    for (int k = 1; k < 4; k++) {
        f32x4 t = reinterpret_cast<const f32x4*>(pbuf + (long)k * 1048576)[i];
        s[0] += t[0]; s[1] += t[1]; s[2] += t[2]; s[3] += t[3];
    }
    int col4 = (i << 2) & 1023;
    f32x4 bv = *(const f32x4*)&bias[col4];
    s[0] += bv[0]; s[1] += bv[1]; s[2] += bv[2]; s[3] += bv[3];
    reinterpret_cast<f32x4*>(outF)[i] = s;
    bf16x4 h = { (bf16)s[0], (bf16)s[1], (bf16)s[2], (bf16)s[3] };
    reinterpret_cast<bf16x4*>(outB)[i] = h;
}

// ---------------------------------------------------------------------------
// Prologue bodies
// ---------------------------------------------------------------------------
__device__ __forceinline__ void transpose_body(
    int bx, int by, const float* __restrict__ in, bf16* __restrict__ out,
    int R, int C, float* t /* 32*33 floats */)
{
    int c0 = bx * 32, r0 = by * 32;
    int tx = threadIdx.x & 31, ty = threadIdx.x >> 5;
#pragma unroll
    for (int i = 0; i < 32; i += 8)
        t[(ty + i) * 33 + tx] = in[(long)(r0 + ty + i) * C + c0 + tx];
    __syncthreads();
#pragma unroll
    for (int i = 0; i < 32; i += 8)
        out[(long)(c0 + ty + i) * R + r0 + tx] = (bf16)t[tx * 33 + ty + i];
}

__device__ __forceinline__ void convw_body(
    int o, const float* __restrict__ cw, bf16* __restrict__ out, float* t /*4096*/)
{
    const float* src = cw + (long)o * 4096;
    bf16* dst = out + (long)o * 4096;
#pragma unroll
    for (int k = 0; k < 4; k++)
        *(f32x4*)&t[(threadIdx.x + k * 256) * 4] = *(const f32x4*)&src[(threadIdx.x + k * 256) * 4];
    __syncthreads();
#pragma unroll
    for (int k = 0; k < 8; k++) {
        int d2 = 2 * (threadIdx.x + k * 256);
        int pi = ((d2 & 1023) << 2) | (d2 >> 10);
        bf16x2 h = { (bf16)t[pi], (bf16)t[pi + 4] };
        *(bf16x2*)&dst[d2] = h;
    }
}

// prologue: Wq T | Wkv T | Wout T | convw | casts
__global__ __launch_bounds__(256)
void prologue_kernel(const float* __restrict__ Wq, bf16* __restrict__ WqTb,
                     const float* __restrict__ Wkv, bf16* __restrict__ WkvTb,
                     const float* __restrict__ Wout, bf16* __restrict__ WoutTb,
                     const float* __restrict__ conv_w, bf16* __restrict__ convwTb,
                     const float* __restrict__ pe, bf16* __restrict__ peb,
                     const float* __restrict__ x, bf16* __restrict__ xb,
                     const float* __restrict__ mem, bf16* __restrict__ memb,
                     const float* __restrict__ cmem, bf16* __restrict__ cmemb,
                     float* __restrict__ xmirror)
{
    __shared__ float t[4096];
    int gid = blockIdx.x;
    if (gid < 1024) {
        transpose_body(gid & 31, gid >> 5, Wq, WqTb, 1024, 1024, t);
    } else if (gid < 3072) {
        int g = gid - 1024;
        transpose_body(g & 63, g >> 6, Wkv, WkvTb, 1024, 2048, t);
    } else if (gid < 4096) {
        int g = gid - 3072;
        transpose_body(g & 31, g >> 5, Wout, WoutTb, 1024, 1024, t);
    } else if (gid < 5120) {
        convw_body(gid - 4096, conv_w, convwTb, t);
    } else {
        int i0 = (gid - 5120) * 256 + threadIdx.x;
        const int n0 = 294912, n1 = 1048576, n2 = 1048576, n3 = 262144;
        for (int i = i0; i < n0 + n1 + n2 + n3; i += 2048 * 256) {
            const float* src; bf16* dst; int k = i; int seg;
            if (k < n0) { src = pe; dst = peb; seg = 0; }
            else if ((k -= n0) < n1) { src = x; dst = xb; seg = 1; }
            else if ((k -= n1) < n2) { src = mem; dst = memb; seg = 2; }
            else { k -= n2; src = cmem; dst = cmemb; seg = 3; }
            f32x4 f = reinterpret_cast<const f32x4*>(src)[k];
            bf16x4 h = { (bf16)f[0], (bf16)f[1], (bf16)f[2], (bf16)f[3] };
            reinterpret_cast<bf16x4*>(dst)[k] = h;
            if (seg == 1)
                __builtin_nontemporal_store(f, &reinterpret_cast<f32x4*>(xmirror)[k]);
        }
    }
}

__global__ __launch_bounds__(256)
void aux_reduce_kernel(const float* __restrict__ partials, float* __restrict__ out)
{
    int tid = threadIdx.x;
    __shared__ float wred[4];
    float s = 0.f;
    for (int i = tid; i < 512; i += 256) s += partials[i];
#pragma unroll
    for (int off = 32; off; off >>= 1) s += __shfl_xor(s, off, 64);
    if ((tid & 63) == 0) wred[tid >> 6] = s;
    __syncthreads();
    if (tid == 0) out[0] = (wred[0] + wred[1] + wred[2] + wred[3]) * (1.0f / 4194304.0f);
}

extern "C" void kernel_launch(void* const* d_in, const int* in_sizes, int n_in,
                              void* d_out, int out_size, void* d_ws, size_t ws_size,
                              hipStream_t stream)
{
    const float* x      = (const float*)d_in[0];
    const float* mem    = (const float*)d_in[1];
    const float* cmem   = (const float*)d_in[2];
    const float* pe     = (const float*)d_in[3];
    const float* Wq     = (const float*)d_in[4];
    const float* Wkv    = (const float*)d_in[5];
    const float* Wout   = (const float*)d_in[6];
    const float* bout   = (const float*)d_in[7];
    const float* conv_w = (const float*)d_in[8];
    const float* conv_b = (const float*)d_in[9];

    float* out_logits  = (float*)d_out;                 // 8*512*1024
    float* out_newmem  = out_logits + 4194304;          // 8*512*1024
    float* out_newcmem = out_newmem + 4194304;          // 8*128*1024
    float* out_aux     = out_newcmem + 1048576;         // 1
    float* out_weights = out_aux + 1;                   // 8*16*512*1152

    float* ws       = (float*)d_ws;
    float* partials = ws;                    // 4096 f
    float* pbuf     = partials + 4096;       // 4 * 1,048,576 f
    bf16* bws     = (bf16*)(pbuf + 4194304);
    bf16* WqTb    = bws;                     // 1,048,576
    bf16* WkvTb   = WqTb + 1048576;          // 2,097,152
    bf16* WoutTb  = WkvTb + 2097152;         // 1,048,576
    bf16* convwTb = WoutTb + 1048576;        // 4,194,304
    bf16* vTb     = convwTb + 4194304;       // 9,437,184
    bf16* cvT     = vTb + 9437184;           // 1,048,576
    bf16* qb      = cvT + 1048576;           // 4,194,304
    bf16* kb      = qb + 4194304;            // 9,437,184
    bf16* ckb     = kb + 9437184;            // 1,048,576
    bf16* peb     = ckb + 1048576;           // 1,179,648
    bf16* xb      = peb + 1179648;           // 4,194,304
    bf16* memb    = xb + 4194304;            // 4,194,304
    bf16* cmemb   = memb + 4194304;          // 1,048,576
    bf16* ncmemb  = cmemb + 1048576;         // 1,048,576
    bf16* oatb    = ncmemb + 1048576;        // 4,194,304

    dim3 blk(256);

    // merged prologue: weight transposes + convw cast + input casts
    prologue_kernel<<<dim3(7168), blk, 0, stream>>>(
        Wq, WqTb, Wkv, WkvTb, Wout, WoutTb, conv_w, convwTb,
        pe, peb, x, xb, mem, memb, cmem, cmemb, out_newmem);

    // Launch A: kv + q + conv split-K
    gemmA_kernel<<<dim3(1664), blk, 0, stream>>>(
        xb, memb, cmemb, WqTb, WkvTb, convwTb, qb, kb, vTb, pbuf);

    // reduce partials + bias -> new_cmem (fp32) + ncmemb (bf16)
    splitk_reduce<<<dim3(1024), blk, 0, stream>>>(pbuf, conv_b, out_newcmem, ncmemb);

    // ckv standalone (128 blocks)
    ckv_kernel<<<dim3(128), blk, 0, stream>>>(ncmemb, WkvTb, ckb, cvT);

    // fused attention (standalone, 52 VGPR)
    attn_fused16<<<dim3(4096), blk, 0, stream>>>(qb, kb, peb, vTb, out_weights, oatb);

    // Launch C: aux + logits
    logits_aux_kernel<<<dim3(768), blk, 0, stream>>>(
        qb, kb, ckb, vTb, cvT, partials, oatb, WoutTb, out_logits, bout);

    aux_reduce_kernel<<<dim3(1), blk, 0, stream>>>(partials, out_aux);
}